// Round 5
// baseline (1614.003 us; speedup 1.0000x reference)
//
#include <hip/hip_runtime.h>

#define LEAKY_SLOPE 0.01f
#define BSHIFT 7              // 128 nodes per bucket
#define BNODES 128
#define CHUNK 8192            // edges per bucket_scatter block

__device__ __forceinline__ float leaky_f(float x) { return x > 0.f ? x : LEAKY_SLOPE * x; }

// ---------------------------------------------------------------------------
// Combine THETAS (compile-time, D=2) with W3 (192x64).
// ---------------------------------------------------------------------------
__global__ void compute_M(const float* __restrict__ W3, float* __restrict__ M) {
    int idx = blockIdx.x * blockDim.x + threadIdx.x;
    if (idx >= 192 * 64) return;
    int c = idx & 63;
    int r = (idx >> 6) & 63;
    int k = idx >> 12;  // 0..2
    const float TH[3][3] = {{3.f, -3.f, 0.75f},
                            {0.f,  3.f, -1.5f},
                            {0.f,  0.f, 0.75f}};
    float v = 0.f;
    #pragma unroll
    for (int t = 0; t < 3; t++) v += TH[t][k] * W3[(t * 64 + r) * 64 + c];
    M[idx] = v;
}

// ---------------------------------------------------------------------------
// Batched graph over BOTH relations: 2N nodes, 2E edges (branch1 at N..2N-1).
// ---------------------------------------------------------------------------
__global__ void deg2_kernel(const int* __restrict__ dst0, const int* __restrict__ dst1,
                            int* __restrict__ deg, int N, int E) {
    int e = blockIdx.x * blockDim.x + threadIdx.x;
    if (e >= 2 * E) return;
    int idx = (e >= E) ? (N + dst1[e - E]) : dst0[e];
    atomicAdd(&deg[idx], 1);
}

__global__ void scan1(const int* __restrict__ deg, int* __restrict__ incl,
                      int* __restrict__ bsum, int n) {
    __shared__ int sm[1024];
    int i = blockIdx.x * 1024 + threadIdx.x;
    int v = (i < n) ? deg[i] : 0;
    sm[threadIdx.x] = v;
    __syncthreads();
    for (int off = 1; off < 1024; off <<= 1) {
        int a = (threadIdx.x >= (unsigned)off) ? sm[threadIdx.x - off] : 0;
        __syncthreads();
        sm[threadIdx.x] += a;
        __syncthreads();
    }
    if (i < n) incl[i] = sm[threadIdx.x];
    if (threadIdx.x == 1023) bsum[blockIdx.x] = sm[1023];
}

__global__ void scan2(int* __restrict__ bsum, int nb) {
    __shared__ int sm[128];
    int t = threadIdx.x;
    int v = (t < nb) ? bsum[t] : 0;
    sm[t] = v;
    __syncthreads();
    for (int off = 1; off < 128; off <<= 1) {
        int a = (t >= off) ? sm[t - off] : 0;
        __syncthreads();
        sm[t] += a;
        __syncthreads();
    }
    if (t < nb) bsum[t] = sm[t] - v;  // exclusive
}

__global__ void scan3(const int* __restrict__ incl, const int* __restrict__ bsum,
                      const int* __restrict__ deg, int* __restrict__ rowptr,
                      float* __restrict__ dinv, float* __restrict__ rsb, int n) {
    int i = blockIdx.x * blockDim.x + threadIdx.x;
    if (i >= n) return;
    int inc = incl[i] + bsum[i >> 10];
    rowptr[i + 1] = inc;
    if (i == 0) rowptr[0] = 0;
    int d = deg[i];
    float df = (float)(d < 1 ? 1 : d);
    float sq = sqrtf(df);
    rsb[i] = sq;           // sqrt(clip(deg,1))  (unscale)
    dinv[i] = 1.0f / sq;   // clip(deg,1)^(-1/2)
}

__global__ void bcinit(const int* __restrict__ rowptr, int* __restrict__ bcursor, int nbuck) {
    int b = blockIdx.x * blockDim.x + threadIdx.x;
    if (b < nbuck) bcursor[b] = rowptr[b << BSHIFT];
}

// ---------------------------------------------------------------------------
// LDS-binned bucket scatter. Each block: histogram its 8192-edge chunk over
// 782 dst-buckets (LDS atomics), reserve contiguous global segments (one
// global atomic per non-empty bucket), then write payloads into its private
// segments -> lines are dirtied by 1-2 blocks instead of 16 random ones.
// Payload: (dst & 127) << 17 | global_src   (24 bits).
// ---------------------------------------------------------------------------
__global__ void bucket_scatter(const int* __restrict__ src0, const int* __restrict__ dst0,
                               const int* __restrict__ src1, const int* __restrict__ dst1,
                               int* __restrict__ bcursor, int* __restrict__ ebuf,
                               int N, int E, int nbuck) {
    __shared__ int hist[1024];
    __shared__ int cur[1024];
    int e0 = blockIdx.x * CHUNK;
    int e1 = min(e0 + CHUNK, 2 * E);
    for (int i = threadIdx.x; i < nbuck; i += 256) hist[i] = 0;
    __syncthreads();
    for (int e = e0 + threadIdx.x; e < e1; e += 256) {
        int d = (e >= E) ? (N + dst1[e - E]) : dst0[e];
        atomicAdd(&hist[d >> BSHIFT], 1);
    }
    __syncthreads();
    for (int i = threadIdx.x; i < nbuck; i += 256) {
        int c = hist[i];
        cur[i] = (c > 0) ? atomicAdd(&bcursor[i], c) : 0;
    }
    __syncthreads();
    for (int e = e0 + threadIdx.x; e < e1; e += 256) {
        int s, d;
        if (e >= E) { s = N + src1[e - E]; d = N + dst1[e - E]; }
        else        { s = src0[e];         d = dst0[e]; }
        int b = d >> BSHIFT;
        int pos = atomicAdd(&cur[b], 1);
        ebuf[pos] = ((d & (BNODES - 1)) << 17) | s;
    }
}

// ---------------------------------------------------------------------------
// SpMM on pre-scaled features, one block per 128-node bucket.
// LDS accumulator 128x64 f32 (32KB). Wave-per-edge: gather Fin[src*64+lane],
// ds_add_f32 into acc[dstLow*64+lane] (lane-consecutive -> conflict-free).
// Epilogue: Fout[u] = Fin[u] - dinv[u]^2 * acc[u]  (coalesced).
// ---------------------------------------------------------------------------
__global__ void spmm_bucket(const float* __restrict__ Fin, float* __restrict__ Fout,
                            const int* __restrict__ rowptr, const int* __restrict__ ebuf,
                            const float* __restrict__ dinv, int n2) {
    __shared__ float acc[BNODES * 64];
    int node0 = blockIdx.x << BSHIFT;
    for (int i = threadIdx.x; i < BNODES * 64; i += 256) acc[i] = 0.f;
    __syncthreads();
    int beg = rowptr[node0];
    int end = rowptr[min(node0 + BNODES, n2)];
    int lane = threadIdx.x & 63;
    int w = threadIdx.x >> 6;  // 0..3
    const float* base = Fin + lane;
    int e = beg + w;
    for (; e + 4 < end; e += 8) {
        int p0 = ebuf[e];
        int p1 = ebuf[e + 4];
        float v0 = base[(p0 & 0x1FFFF) * 64];
        float v1 = base[(p1 & 0x1FFFF) * 64];
        atomicAdd(&acc[((p0 >> 17) << 6) + lane], v0);
        atomicAdd(&acc[((p1 >> 17) << 6) + lane], v1);
    }
    for (; e < end; e += 4) {
        int p = ebuf[e];
        atomicAdd(&acc[((p >> 17) << 6) + lane], base[(p & 0x1FFFF) * 64]);
    }
    __syncthreads();
    for (int i = threadIdx.x; i < BNODES * 64; i += 256) {
        int u = node0 + (i >> 6);
        if (u < n2) {
            float di = dinv[u];
            size_t gi = (size_t)u * 64 + (i & 63);
            Fout[gi] = Fin[gi] - di * di * acc[i];
        }
    }
}

// ---------------------------------------------------------------------------
// MLP GEMM, both branches in one dispatch. LDS-staged W, 2 rows/thread.
// SCALE: epilogue writes leaky(y)*dinv[u].
// ---------------------------------------------------------------------------
template <int K, bool SCALE>
__global__ void gemm_mlp(const float* __restrict__ A0, const float* __restrict__ A1, int lda,
                         const float* __restrict__ Wg0, const float* __restrict__ Wg1,
                         const float* __restrict__ bias0, const float* __restrict__ bias1,
                         const float* __restrict__ dinv, float* __restrict__ out64,
                         int N, int GB) {
    __shared__ float Ws[K * 64];
    __shared__ float bs[64];
    int br = (blockIdx.x >= GB) ? 1 : 0;
    const float* Wg = br ? Wg1 : Wg0;
    const float* bias = br ? bias1 : bias0;
    for (int i = threadIdx.x; i < K * 16; i += 256)
        reinterpret_cast<float4*>(Ws)[i] = reinterpret_cast<const float4*>(Wg)[i];
    if (threadIdx.x < 64) bs[threadIdx.x] = bias[threadIdx.x];
    __syncthreads();

    int lane = threadIdx.x & 63;
    int c0 = (threadIdx.x >> 6) * 16;
    int bb = blockIdx.x - br * GB;
    int r0 = bb * 128 + lane;
    int r1 = r0 + 64;
    bool v0 = r0 < N, v1 = r1 < N;
    int r0c = v0 ? r0 : N - 1;
    int r1c = v1 ? r1 : N - 1;
    const float* A = br ? A1 : A0;

    float acc0[16], acc1[16];
    #pragma unroll
    for (int j = 0; j < 16; j++) { acc0[j] = bs[c0 + j]; acc1[j] = bs[c0 + j]; }

    const float4* a0p = reinterpret_cast<const float4*>(A + (size_t)r0c * lda);
    const float4* a1p = reinterpret_cast<const float4*>(A + (size_t)r1c * lda);
    #pragma unroll 1
    for (int k4 = 0; k4 < K / 4; k4++) {
        float4 a0 = a0p[k4];
        float4 a1 = a1p[k4];
        #pragma unroll
        for (int kk = 0; kk < 4; kk++) {
            float a0k = (kk == 0) ? a0.x : (kk == 1) ? a0.y : (kk == 2) ? a0.z : a0.w;
            float a1k = (kk == 0) ? a1.x : (kk == 1) ? a1.y : (kk == 2) ? a1.z : a1.w;
            const float4* wrow = reinterpret_cast<const float4*>(Ws + (k4 * 4 + kk) * 64 + c0);
            #pragma unroll
            for (int j4 = 0; j4 < 4; j4++) {
                float4 w = wrow[j4];
                acc0[j4 * 4 + 0] += a0k * w.x; acc0[j4 * 4 + 1] += a0k * w.y;
                acc0[j4 * 4 + 2] += a0k * w.z; acc0[j4 * 4 + 3] += a0k * w.w;
                acc1[j4 * 4 + 0] += a1k * w.x; acc1[j4 * 4 + 1] += a1k * w.y;
                acc1[j4 * 4 + 2] += a1k * w.z; acc1[j4 * 4 + 3] += a1k * w.w;
            }
        }
    }

    float s0 = SCALE ? dinv[br * N + r0c] : 1.f;
    float s1 = SCALE ? dinv[br * N + r1c] : 1.f;
    if (v0) {
        float* o = out64 + (size_t)(br * N + r0) * 64 + c0;
        #pragma unroll
        for (int j = 0; j < 16; j++) { float v = leaky_f(acc0[j]); if (SCALE) v *= s0; o[j] = v; }
    }
    if (v1) {
        float* o = out64 + (size_t)(br * N + r1) * 64 + c0;
        #pragma unroll
        for (int j = 0; j < 16; j++) { float v = leaky_f(acc1[j]); if (SCALE) v *= s1; o[j] = v; }
    }
}

// ---------------------------------------------------------------------------
// Final fused GEMM: out = leaky( sum_{branch} [h|f1|f2]@M + 2*b3 ).
// Unscale (x rsb[row]) fused into A loads. M staged in LDS (48KB).
// ---------------------------------------------------------------------------
__global__ void gemmF(const float* __restrict__ Hs, const float* __restrict__ F1s,
                      const float* __restrict__ F2s, const float* __restrict__ rsb,
                      const float* __restrict__ Mg, const float* __restrict__ b3,
                      float* __restrict__ out, int N) {
    __shared__ float Ms[192 * 64];
    __shared__ float bs[64];
    for (int i = threadIdx.x; i < 192 * 16; i += 256)
        reinterpret_cast<float4*>(Ms)[i] = reinterpret_cast<const float4*>(Mg)[i];
    if (threadIdx.x < 64) bs[threadIdx.x] = 2.f * b3[threadIdx.x];
    __syncthreads();

    int lane = threadIdx.x & 63;
    int c0 = (threadIdx.x >> 6) * 16;
    int r0 = blockIdx.x * 128 + lane;
    int r1 = r0 + 64;
    bool v0 = r0 < N, v1 = r1 < N;
    int r0c = v0 ? r0 : N - 1;
    int r1c = v1 ? r1 : N - 1;

    float acc0[16], acc1[16];
    #pragma unroll
    for (int j = 0; j < 16; j++) { acc0[j] = bs[c0 + j]; acc1[j] = bs[c0 + j]; }

    #pragma unroll
    for (int half = 0; half < 2; half++) {
        int ub = half * N;
        float s0 = rsb[ub + r0c];
        float s1 = rsb[ub + r1c];
        #pragma unroll
        for (int pa = 0; pa < 3; pa++) {
            const float* P = (pa == 0) ? Hs : (pa == 1) ? F1s : F2s;
            const float4* a0p = reinterpret_cast<const float4*>(P + (size_t)(ub + r0c) * 64);
            const float4* a1p = reinterpret_cast<const float4*>(P + (size_t)(ub + r1c) * 64);
            #pragma unroll 1
            for (int k4 = 0; k4 < 16; k4++) {
                float4 a0 = a0p[k4];
                float4 a1 = a1p[k4];
                a0.x *= s0; a0.y *= s0; a0.z *= s0; a0.w *= s0;
                a1.x *= s1; a1.y *= s1; a1.z *= s1; a1.w *= s1;
                #pragma unroll
                for (int kk = 0; kk < 4; kk++) {
                    float a0k = (kk == 0) ? a0.x : (kk == 1) ? a0.y : (kk == 2) ? a0.z : a0.w;
                    float a1k = (kk == 0) ? a1.x : (kk == 1) ? a1.y : (kk == 2) ? a1.z : a1.w;
                    const float4* wrow =
                        reinterpret_cast<const float4*>(Ms + (pa * 64 + k4 * 4 + kk) * 64 + c0);
                    #pragma unroll
                    for (int j4 = 0; j4 < 4; j4++) {
                        float4 w = wrow[j4];
                        acc0[j4 * 4 + 0] += a0k * w.x; acc0[j4 * 4 + 1] += a0k * w.y;
                        acc0[j4 * 4 + 2] += a0k * w.z; acc0[j4 * 4 + 3] += a0k * w.w;
                        acc1[j4 * 4 + 0] += a1k * w.x; acc1[j4 * 4 + 1] += a1k * w.y;
                        acc1[j4 * 4 + 2] += a1k * w.z; acc1[j4 * 4 + 3] += a1k * w.w;
                    }
                }
            }
        }
    }

    if (v0) {
        float* o = out + (size_t)r0 * 64 + c0;
        #pragma unroll
        for (int j = 0; j < 16; j++) o[j] = leaky_f(acc0[j]);
    }
    if (v1) {
        float* o = out + (size_t)r1 * 64 + c0;
        #pragma unroll
        for (int j = 0; j < 16; j++) o[j] = leaky_f(acc1[j]);
    }
}

// ---------------------------------------------------------------------------
extern "C" void kernel_launch(void* const* d_in, const int* in_sizes, int n_in,
                              void* d_out, int out_size, void* d_ws, size_t ws_size,
                              hipStream_t stream) {
    const int N = in_sizes[0] / 128;
    const int E = in_sizes[2];
    const int N2 = 2 * N;
    const int NBUCK = (N2 + BNODES - 1) >> BSHIFT;

    const float* feat0 = (const float*)d_in[0];
    const float* feat1 = (const float*)d_in[1];
    const int*   src0  = (const int*)d_in[2];
    const int*   dst0  = (const int*)d_in[3];
    const int*   src1  = (const int*)d_in[4];
    const int*   dst1  = (const int*)d_in[5];
    const float* W1_0  = (const float*)d_in[6];
    const float* b1_0  = (const float*)d_in[7];
    const float* W2_0  = (const float*)d_in[8];
    const float* b2_0  = (const float*)d_in[9];
    const float* W1_1  = (const float*)d_in[10];
    const float* b1_1  = (const float*)d_in[11];
    const float* W2_1  = (const float*)d_in[12];
    const float* b2_1  = (const float*)d_in[13];
    const float* W3    = (const float*)d_in[14];
    const float* b3    = (const float*)d_in[15];
    float* out = (float*)d_out;

    char* p = (char*)d_ws;
    auto alloc = [&](size_t bytes) -> char* {
        char* r = p;
        p += (bytes + 255) & ~(size_t)255;
        return r;
    };
    float* Mcat    = (float*)alloc((size_t)192 * 64 * 4);
    float* Hs      = (float*)alloc((size_t)N2 * 64 * 4);   // h * dinv
    float* F1s     = (float*)alloc((size_t)N2 * 64 * 4);   // f1 * dinv
    float* F2s     = (float*)alloc((size_t)N2 * 64 * 4);   // f2 * dinv (aliases MLP tmp)
    float* dinv    = (float*)alloc((size_t)N2 * 4);
    float* rsb     = (float*)alloc((size_t)N2 * 4);
    int*   deg     = (int*)alloc((size_t)N2 * 4);
    int*   rowptr  = (int*)alloc((size_t)(N2 + 1) * 4);
    int*   bcursor = (int*)alloc((size_t)NBUCK * 4);
    int*   ebuf    = (int*)alloc((size_t)2 * E * 4);
    int*   incl    = (int*)alloc((size_t)N2 * 4);
    int*   bsum    = (int*)alloc((size_t)128 * 4);
    float* tmp     = F2s;  // MLP hidden; dead before spmm2 writes F2s
    (void)ws_size; (void)n_in; (void)out_size;

    const int NB = (N2 + 1023) / 1024;   // 98 (<128, fits scan2)
    const int GB = (N + 127) / 128;

    compute_M<<<(192 * 64 + 255) / 256, 256, 0, stream>>>(W3, Mcat);

    // --- batched graph build ---
    hipMemsetAsync(deg, 0, (size_t)N2 * 4, stream);
    deg2_kernel<<<(2 * E + 255) / 256, 256, 0, stream>>>(dst0, dst1, deg, N, E);
    scan1<<<NB, 1024, 0, stream>>>(deg, incl, bsum, N2);
    scan2<<<1, 128, 0, stream>>>(bsum, NB);
    scan3<<<(N2 + 255) / 256, 256, 0, stream>>>(incl, bsum, deg, rowptr, dinv, rsb, N2);
    bcinit<<<(NBUCK + 255) / 256, 256, 0, stream>>>(rowptr, bcursor, NBUCK);
    bucket_scatter<<<(2 * E + CHUNK - 1) / CHUNK, 256, 0, stream>>>(
        src0, dst0, src1, dst1, bcursor, ebuf, N, E, NBUCK);

    // --- MLP (both branches): tmp = leaky(X@W1+b1); Hs = leaky(tmp@W2+b2)*dinv ---
    gemm_mlp<128, false><<<2 * GB, 256, 0, stream>>>(
        feat0, feat1, 128, W1_0, W1_1, b1_0, b1_1, dinv, tmp, N, GB);
    gemm_mlp<64, true><<<2 * GB, 256, 0, stream>>>(
        tmp, tmp + (size_t)N * 64, 64, W2_0, W2_1, b2_0, b2_1, dinv, Hs, N, GB);

    // --- polynomial propagation on scaled features (bucket-grouped edges) ---
    spmm_bucket<<<NBUCK, 256, 0, stream>>>(Hs, F1s, rowptr, ebuf, dinv, N2);
    spmm_bucket<<<NBUCK, 256, 0, stream>>>(F1s, F2s, rowptr, ebuf, dinv, N2);

    // --- out = leaky( sum_b [h|f1|f2]@M + 2*b3 ), unscale fused ---
    gemmF<<<(N + 127) / 128, 256, 0, stream>>>(Hs, F1s, F2s, rsb, Mcat, b3, out, N);
}

// Round 6
// 320.311 us; speedup vs baseline: 5.0389x; 5.0389x over previous
//
#include <hip/hip_runtime.h>

#define LEAKY_SLOPE 0.01f
#define BSHIFT 7              // 128 nodes per bucket
#define BNODES 128
#define CHUNK 8192            // edges per chunked block

__device__ __forceinline__ float leaky_f(float x) { return x > 0.f ? x : LEAKY_SLOPE * x; }

// ---------------------------------------------------------------------------
// Combine THETAS (compile-time, D=2) with W3 (192x64).
// ---------------------------------------------------------------------------
__global__ void compute_M(const float* __restrict__ W3, float* __restrict__ M) {
    int idx = blockIdx.x * blockDim.x + threadIdx.x;
    if (idx >= 192 * 64) return;
    int c = idx & 63;
    int r = (idx >> 6) & 63;
    int k = idx >> 12;  // 0..2
    const float TH[3][3] = {{3.f, -3.f, 0.75f},
                            {0.f,  3.f, -1.5f},
                            {0.f,  0.f, 0.75f}};
    float v = 0.f;
    #pragma unroll
    for (int t = 0; t < 3; t++) v += TH[t][k] * W3[(t * 64 + r) * 64 + c];
    M[idx] = v;
}

// ---------------------------------------------------------------------------
// K1: per-bucket edge counts. LDS histogram per chunk, then one global
// atomic per (block, non-empty bucket).
// ---------------------------------------------------------------------------
__global__ void bcount(const int* __restrict__ dst0, const int* __restrict__ dst1,
                       int* __restrict__ bcnt, int N, int E, int nbuck) {
    __shared__ int hist[1024];
    int e0 = blockIdx.x * CHUNK;
    int e1 = min(e0 + CHUNK, 2 * E);
    for (int i = threadIdx.x; i < nbuck; i += 256) hist[i] = 0;
    __syncthreads();
    for (int e = e0 + threadIdx.x; e < e1; e += 256) {
        int d = (e >= E) ? (N + dst1[e - E]) : dst0[e];
        atomicAdd(&hist[d >> BSHIFT], 1);
    }
    __syncthreads();
    for (int i = threadIdx.x; i < nbuck; i += 256) {
        int c = hist[i];
        if (c > 0) atomicAdd(&bcnt[i], c);
    }
}

// ---------------------------------------------------------------------------
// K2: exclusive scan over <=1024 bucket counts (one block), emits bbase
// (nbuck+1 entries) and initializes bcursor = bbase. rowptr[0] = 0.
// ---------------------------------------------------------------------------
__global__ void bscan(const int* __restrict__ bcnt, int* __restrict__ bbase,
                      int* __restrict__ bcursor, int* __restrict__ rowptr, int nbuck) {
    __shared__ int sm[1024];
    int t = threadIdx.x;
    int v = (t < nbuck) ? bcnt[t] : 0;
    sm[t] = v;
    __syncthreads();
    for (int off = 1; off < 1024; off <<= 1) {
        int a = (t >= off) ? sm[t - off] : 0;
        __syncthreads();
        sm[t] += a;
        __syncthreads();
    }
    if (t < nbuck) {
        int excl = sm[t] - v;
        bbase[t] = excl;
        bcursor[t] = excl;
        if (t == nbuck - 1) bbase[nbuck] = sm[t];
    }
    if (t == 0) rowptr[0] = 0;
}

// ---------------------------------------------------------------------------
// K3: clustered scatter into per-bucket segments. Payload:
// (dst & 127) << 17 | global_src.
// ---------------------------------------------------------------------------
__global__ void bucket_scatter(const int* __restrict__ src0, const int* __restrict__ dst0,
                               const int* __restrict__ src1, const int* __restrict__ dst1,
                               int* __restrict__ bcursor, int* __restrict__ ebuf,
                               int N, int E, int nbuck) {
    __shared__ int hist[1024];
    __shared__ int cur[1024];
    int e0 = blockIdx.x * CHUNK;
    int e1 = min(e0 + CHUNK, 2 * E);
    for (int i = threadIdx.x; i < nbuck; i += 256) hist[i] = 0;
    __syncthreads();
    for (int e = e0 + threadIdx.x; e < e1; e += 256) {
        int d = (e >= E) ? (N + dst1[e - E]) : dst0[e];
        atomicAdd(&hist[d >> BSHIFT], 1);
    }
    __syncthreads();
    for (int i = threadIdx.x; i < nbuck; i += 256) {
        int c = hist[i];
        cur[i] = (c > 0) ? atomicAdd(&bcursor[i], c) : 0;
    }
    __syncthreads();
    for (int e = e0 + threadIdx.x; e < e1; e += 256) {
        int s, d;
        if (e >= E) { s = N + src1[e - E]; d = N + dst1[e - E]; }
        else        { s = src0[e];         d = dst0[e]; }
        int b = d >> BSHIFT;
        int pos = atomicAdd(&cur[b], 1);
        ebuf[pos] = ((d & (BNODES - 1)) << 17) | s;
    }
}

// ---------------------------------------------------------------------------
// K4: per-bucket local counting sort -> node-sorted edge array (payload
// src*64), per-node rowptr/dinv/rsb. Coalesced segment reads; writes land
// inside this block's contiguous segment (L2-merged, no line amplification).
// ---------------------------------------------------------------------------
__global__ void bucket_sort(const int* __restrict__ ebuf_in, const int* __restrict__ bbase,
                            int* __restrict__ ebuf_out, int* __restrict__ rowptr,
                            float* __restrict__ dinv, float* __restrict__ rsb, int n2) {
    __shared__ int hist[BNODES];
    __shared__ int scan[BNODES];
    __shared__ int cur[BNODES];
    int b = blockIdx.x;
    int node0 = b << BSHIFT;
    int beg = bbase[b];
    int end = bbase[b + 1];
    int t = threadIdx.x;
    if (t < BNODES) hist[t] = 0;
    __syncthreads();
    for (int e = beg + t; e < end; e += 256)
        atomicAdd(&hist[(unsigned)ebuf_in[e] >> 17], 1);
    __syncthreads();
    if (t < BNODES) scan[t] = hist[t];
    __syncthreads();
    #pragma unroll
    for (int off = 1; off < BNODES; off <<= 1) {
        int a = (t < BNODES && t >= off) ? scan[t - off] : 0;
        __syncthreads();
        if (t < BNODES) scan[t] += a;
        __syncthreads();
    }
    int nvalid = min(BNODES, n2 - node0);
    if (t < nvalid) {
        int d = hist[t];
        int incl = scan[t];
        rowptr[node0 + t + 1] = beg + incl;
        cur[t] = beg + incl - d;
        float df = (float)(d < 1 ? 1 : d);
        float sq = sqrtf(df);
        rsb[node0 + t] = sq;
        dinv[node0 + t] = 1.0f / sq;
    }
    __syncthreads();
    for (int e = beg + t; e < end; e += 256) {
        int p = ebuf_in[e];
        int pos = atomicAdd(&cur[(unsigned)p >> 17], 1);
        ebuf_out[pos] = (p & 0x1FFFF) << 6;
    }
}

// ---------------------------------------------------------------------------
// SpMM on pre-scaled features: Fout[u] = Fin[u] - dinv[u]^2 * sum Fin[src].
// One wave per node, lane = feature. 8 gathers in flight per wave.
// ---------------------------------------------------------------------------
__global__ void spmm_s(const float* __restrict__ Fin, float* __restrict__ Fout,
                       const int* __restrict__ rowptr, const int* __restrict__ epay,
                       const float* __restrict__ dinv, int n2) {
    int u = (blockIdx.x * blockDim.x + threadIdx.x) >> 6;
    int j = threadIdx.x & 63;
    if (u >= n2) return;
    int beg = rowptr[u];
    int end = rowptr[u + 1];
    const float* base = Fin + j;
    float a0 = 0.f, a1 = 0.f, a2 = 0.f, a3 = 0.f;
    int e = beg;
    for (; e + 8 <= end; e += 8) {
        int o0 = epay[e + 0], o1 = epay[e + 1], o2 = epay[e + 2], o3 = epay[e + 3];
        int o4 = epay[e + 4], o5 = epay[e + 5], o6 = epay[e + 6], o7 = epay[e + 7];
        float v0 = base[o0], v1 = base[o1], v2 = base[o2], v3 = base[o3];
        float v4 = base[o4], v5 = base[o5], v6 = base[o6], v7 = base[o7];
        a0 += v0; a1 += v1; a2 += v2; a3 += v3;
        a0 += v4; a1 += v5; a2 += v6; a3 += v7;
    }
    for (; e + 4 <= end; e += 4) {
        int o0 = epay[e + 0], o1 = epay[e + 1], o2 = epay[e + 2], o3 = epay[e + 3];
        a0 += base[o0]; a1 += base[o1]; a2 += base[o2]; a3 += base[o3];
    }
    for (; e < end; e++) a0 += base[epay[e]];
    float acc = (a0 + a1) + (a2 + a3);
    float di = dinv[u];
    Fout[(size_t)u * 64 + j] = Fin[(size_t)u * 64 + j] - (di * di) * acc;
}

// ---------------------------------------------------------------------------
// MLP GEMM, both branches in one dispatch. LDS-staged W, 2 rows/thread.
// SCALE: epilogue writes leaky(y)*dinv[u].
// ---------------------------------------------------------------------------
template <int K, bool SCALE>
__global__ void gemm_mlp(const float* __restrict__ A0, const float* __restrict__ A1, int lda,
                         const float* __restrict__ Wg0, const float* __restrict__ Wg1,
                         const float* __restrict__ bias0, const float* __restrict__ bias1,
                         const float* __restrict__ dinv, float* __restrict__ out64,
                         int N, int GB) {
    __shared__ float Ws[K * 64];
    __shared__ float bs[64];
    int br = (blockIdx.x >= GB) ? 1 : 0;
    const float* Wg = br ? Wg1 : Wg0;
    const float* bias = br ? bias1 : bias0;
    for (int i = threadIdx.x; i < K * 16; i += 256)
        reinterpret_cast<float4*>(Ws)[i] = reinterpret_cast<const float4*>(Wg)[i];
    if (threadIdx.x < 64) bs[threadIdx.x] = bias[threadIdx.x];
    __syncthreads();

    int lane = threadIdx.x & 63;
    int c0 = (threadIdx.x >> 6) * 16;
    int bb = blockIdx.x - br * GB;
    int r0 = bb * 128 + lane;
    int r1 = r0 + 64;
    bool v0 = r0 < N, v1 = r1 < N;
    int r0c = v0 ? r0 : N - 1;
    int r1c = v1 ? r1 : N - 1;
    const float* A = br ? A1 : A0;

    float acc0[16], acc1[16];
    #pragma unroll
    for (int j = 0; j < 16; j++) { acc0[j] = bs[c0 + j]; acc1[j] = bs[c0 + j]; }

    const float4* a0p = reinterpret_cast<const float4*>(A + (size_t)r0c * lda);
    const float4* a1p = reinterpret_cast<const float4*>(A + (size_t)r1c * lda);
    #pragma unroll 1
    for (int k4 = 0; k4 < K / 4; k4++) {
        float4 a0 = a0p[k4];
        float4 a1 = a1p[k4];
        #pragma unroll
        for (int kk = 0; kk < 4; kk++) {
            float a0k = (kk == 0) ? a0.x : (kk == 1) ? a0.y : (kk == 2) ? a0.z : a0.w;
            float a1k = (kk == 0) ? a1.x : (kk == 1) ? a1.y : (kk == 2) ? a1.z : a1.w;
            const float4* wrow = reinterpret_cast<const float4*>(Ws + (k4 * 4 + kk) * 64 + c0);
            #pragma unroll
            for (int j4 = 0; j4 < 4; j4++) {
                float4 w = wrow[j4];
                acc0[j4 * 4 + 0] += a0k * w.x; acc0[j4 * 4 + 1] += a0k * w.y;
                acc0[j4 * 4 + 2] += a0k * w.z; acc0[j4 * 4 + 3] += a0k * w.w;
                acc1[j4 * 4 + 0] += a1k * w.x; acc1[j4 * 4 + 1] += a1k * w.y;
                acc1[j4 * 4 + 2] += a1k * w.z; acc1[j4 * 4 + 3] += a1k * w.w;
            }
        }
    }

    float s0 = SCALE ? dinv[br * N + r0c] : 1.f;
    float s1 = SCALE ? dinv[br * N + r1c] : 1.f;
    if (v0) {
        float* o = out64 + (size_t)(br * N + r0) * 64 + c0;
        #pragma unroll
        for (int j = 0; j < 16; j++) { float v = leaky_f(acc0[j]); if (SCALE) v *= s0; o[j] = v; }
    }
    if (v1) {
        float* o = out64 + (size_t)(br * N + r1) * 64 + c0;
        #pragma unroll
        for (int j = 0; j < 16; j++) { float v = leaky_f(acc1[j]); if (SCALE) v *= s1; o[j] = v; }
    }
}

// ---------------------------------------------------------------------------
// Final fused GEMM: out = leaky( sum_{branch} [h|f1|f2]@M + 2*b3 ).
// Unscale (x rsb[row]) fused into A loads. M staged in LDS (48KB).
// ---------------------------------------------------------------------------
__global__ void gemmF(const float* __restrict__ Hs, const float* __restrict__ F1s,
                      const float* __restrict__ F2s, const float* __restrict__ rsb,
                      const float* __restrict__ Mg, const float* __restrict__ b3,
                      float* __restrict__ out, int N) {
    __shared__ float Ms[192 * 64];
    __shared__ float bs[64];
    for (int i = threadIdx.x; i < 192 * 16; i += 256)
        reinterpret_cast<float4*>(Ms)[i] = reinterpret_cast<const float4*>(Mg)[i];
    if (threadIdx.x < 64) bs[threadIdx.x] = 2.f * b3[threadIdx.x];
    __syncthreads();

    int lane = threadIdx.x & 63;
    int c0 = (threadIdx.x >> 6) * 16;
    int r0 = blockIdx.x * 128 + lane;
    int r1 = r0 + 64;
    bool v0 = r0 < N, v1 = r1 < N;
    int r0c = v0 ? r0 : N - 1;
    int r1c = v1 ? r1 : N - 1;

    float acc0[16], acc1[16];
    #pragma unroll
    for (int j = 0; j < 16; j++) { acc0[j] = bs[c0 + j]; acc1[j] = bs[c0 + j]; }

    #pragma unroll
    for (int half = 0; half < 2; half++) {
        int ub = half * N;
        float s0 = rsb[ub + r0c];
        float s1 = rsb[ub + r1c];
        #pragma unroll
        for (int pa = 0; pa < 3; pa++) {
            const float* P = (pa == 0) ? Hs : (pa == 1) ? F1s : F2s;
            const float4* a0p = reinterpret_cast<const float4*>(P + (size_t)(ub + r0c) * 64);
            const float4* a1p = reinterpret_cast<const float4*>(P + (size_t)(ub + r1c) * 64);
            #pragma unroll 1
            for (int k4 = 0; k4 < 16; k4++) {
                float4 a0 = a0p[k4];
                float4 a1 = a1p[k4];
                a0.x *= s0; a0.y *= s0; a0.z *= s0; a0.w *= s0;
                a1.x *= s1; a1.y *= s1; a1.z *= s1; a1.w *= s1;
                #pragma unroll
                for (int kk = 0; kk < 4; kk++) {
                    float a0k = (kk == 0) ? a0.x : (kk == 1) ? a0.y : (kk == 2) ? a0.z : a0.w;
                    float a1k = (kk == 0) ? a1.x : (kk == 1) ? a1.y : (kk == 2) ? a1.z : a1.w;
                    const float4* wrow =
                        reinterpret_cast<const float4*>(Ms + (pa * 64 + k4 * 4 + kk) * 64 + c0);
                    #pragma unroll
                    for (int j4 = 0; j4 < 4; j4++) {
                        float4 w = wrow[j4];
                        acc0[j4 * 4 + 0] += a0k * w.x; acc0[j4 * 4 + 1] += a0k * w.y;
                        acc0[j4 * 4 + 2] += a0k * w.z; acc0[j4 * 4 + 3] += a0k * w.w;
                        acc1[j4 * 4 + 0] += a1k * w.x; acc1[j4 * 4 + 1] += a1k * w.y;
                        acc1[j4 * 4 + 2] += a1k * w.z; acc1[j4 * 4 + 3] += a1k * w.w;
                    }
                }
            }
        }
    }

    if (v0) {
        float* o = out + (size_t)r0 * 64 + c0;
        #pragma unroll
        for (int j = 0; j < 16; j++) o[j] = leaky_f(acc0[j]);
    }
    if (v1) {
        float* o = out + (size_t)r1 * 64 + c0;
        #pragma unroll
        for (int j = 0; j < 16; j++) o[j] = leaky_f(acc1[j]);
    }
}

// ---------------------------------------------------------------------------
extern "C" void kernel_launch(void* const* d_in, const int* in_sizes, int n_in,
                              void* d_out, int out_size, void* d_ws, size_t ws_size,
                              hipStream_t stream) {
    const int N = in_sizes[0] / 128;
    const int E = in_sizes[2];
    const int N2 = 2 * N;
    const int NBUCK = (N2 + BNODES - 1) >> BSHIFT;

    const float* feat0 = (const float*)d_in[0];
    const float* feat1 = (const float*)d_in[1];
    const int*   src0  = (const int*)d_in[2];
    const int*   dst0  = (const int*)d_in[3];
    const int*   src1  = (const int*)d_in[4];
    const int*   dst1  = (const int*)d_in[5];
    const float* W1_0  = (const float*)d_in[6];
    const float* b1_0  = (const float*)d_in[7];
    const float* W2_0  = (const float*)d_in[8];
    const float* b2_0  = (const float*)d_in[9];
    const float* W1_1  = (const float*)d_in[10];
    const float* b1_1  = (const float*)d_in[11];
    const float* W2_1  = (const float*)d_in[12];
    const float* b2_1  = (const float*)d_in[13];
    const float* W3    = (const float*)d_in[14];
    const float* b3    = (const float*)d_in[15];
    float* out = (float*)d_out;

    char* p = (char*)d_ws;
    auto alloc = [&](size_t bytes) -> char* {
        char* r = p;
        p += (bytes + 255) & ~(size_t)255;
        return r;
    };
    float* Mcat    = (float*)alloc((size_t)192 * 64 * 4);
    float* Hs      = (float*)alloc((size_t)N2 * 64 * 4);   // h * dinv
    float* F1s     = (float*)alloc((size_t)N2 * 64 * 4);   // f1 * dinv
    float* F2s     = (float*)alloc((size_t)N2 * 64 * 4);   // f2 * dinv (aliases MLP tmp)
    float* dinv    = (float*)alloc((size_t)N2 * 4);
    float* rsb     = (float*)alloc((size_t)N2 * 4);
    int*   rowptr  = (int*)alloc((size_t)(N2 + 1) * 4);
    int*   bcnt    = (int*)alloc((size_t)NBUCK * 4);
    int*   bbase   = (int*)alloc((size_t)(NBUCK + 1) * 4);
    int*   bcursor = (int*)alloc((size_t)NBUCK * 4);
    int*   ebuf1   = (int*)alloc((size_t)2 * E * 4);
    int*   ebuf2   = (int*)alloc((size_t)2 * E * 4);
    float* tmp     = F2s;  // MLP hidden; dead before spmm2 writes F2s
    (void)ws_size; (void)n_in; (void)out_size;

    const int GB = (N + 127) / 128;
    const int ECH = (2 * E + CHUNK - 1) / CHUNK;

    compute_M<<<(192 * 64 + 255) / 256, 256, 0, stream>>>(W3, Mcat);

    // --- graph build: bucket counts -> scan -> clustered scatter -> local sort ---
    hipMemsetAsync(bcnt, 0, (size_t)NBUCK * 4, stream);
    bcount<<<ECH, 256, 0, stream>>>(dst0, dst1, bcnt, N, E, NBUCK);
    bscan<<<1, 1024, 0, stream>>>(bcnt, bbase, bcursor, rowptr, NBUCK);
    bucket_scatter<<<ECH, 256, 0, stream>>>(src0, dst0, src1, dst1, bcursor, ebuf1, N, E, NBUCK);
    bucket_sort<<<NBUCK, 256, 0, stream>>>(ebuf1, bbase, ebuf2, rowptr, dinv, rsb, N2);

    // --- MLP (both branches): tmp = leaky(X@W1+b1); Hs = leaky(tmp@W2+b2)*dinv ---
    gemm_mlp<128, false><<<2 * GB, 256, 0, stream>>>(
        feat0, feat1, 128, W1_0, W1_1, b1_0, b1_1, dinv, tmp, N, GB);
    gemm_mlp<64, true><<<2 * GB, 256, 0, stream>>>(
        tmp, tmp + (size_t)N * 64, 64, W2_0, W2_1, b2_0, b2_1, dinv, Hs, N, GB);

    // --- polynomial propagation on scaled features (node-sorted CSR) ---
    spmm_s<<<(N2 * 64 + 255) / 256, 256, 0, stream>>>(Hs, F1s, rowptr, ebuf2, dinv, N2);
    spmm_s<<<(N2 * 64 + 255) / 256, 256, 0, stream>>>(F1s, F2s, rowptr, ebuf2, dinv, N2);

    // --- out = leaky( sum_b [h|f1|f2]@M + 2*b3 ), unscale fused ---
    gemmF<<<(N + 127) / 128, 256, 0, stream>>>(Hs, F1s, F2s, rsb, Mcat, b3, out, N);
}

// Round 7
// 283.992 us; speedup vs baseline: 5.6833x; 1.1279x over previous
//
#include <hip/hip_runtime.h>

#define LEAKY_SLOPE 0.01f
#define BSHIFT 7              // 128 nodes per bucket
#define BNODES 128
#define CHUNK 8192            // edges per chunked block

typedef unsigned short u16;

__device__ __forceinline__ float leaky_f(float x) { return x > 0.f ? x : LEAKY_SLOPE * x; }

__device__ __forceinline__ float bf2f(u16 b) {
    return __uint_as_float(((unsigned int)b) << 16);
}
__device__ __forceinline__ u16 f2bf(float f) {
    unsigned int u = __float_as_uint(f);
    return (u16)((u + 0x7FFFu + ((u >> 16) & 1u)) >> 16);  // RNE
}
__device__ __forceinline__ float bflo(unsigned int u) { return __uint_as_float(u << 16); }
__device__ __forceinline__ float bfhi(unsigned int u) { return __uint_as_float(u & 0xFFFF0000u); }

// ---------------------------------------------------------------------------
// Combine THETAS (compile-time, D=2) with W3 (192x64).
// ---------------------------------------------------------------------------
__global__ void compute_M(const float* __restrict__ W3, float* __restrict__ M) {
    int idx = blockIdx.x * blockDim.x + threadIdx.x;
    if (idx >= 192 * 64) return;
    int c = idx & 63;
    int r = (idx >> 6) & 63;
    int k = idx >> 12;  // 0..2
    const float TH[3][3] = {{3.f, -3.f, 0.75f},
                            {0.f,  3.f, -1.5f},
                            {0.f,  0.f, 0.75f}};
    float v = 0.f;
    #pragma unroll
    for (int t = 0; t < 3; t++) v += TH[t][k] * W3[(t * 64 + r) * 64 + c];
    M[idx] = v;
}

// ---------------------------------------------------------------------------
// Graph build (unchanged from round 6): bucket counts -> scan -> clustered
// scatter -> per-bucket local counting sort.
// ---------------------------------------------------------------------------
__global__ void bcount(const int* __restrict__ dst0, const int* __restrict__ dst1,
                       int* __restrict__ bcnt, int N, int E, int nbuck) {
    __shared__ int hist[1024];
    int e0 = blockIdx.x * CHUNK;
    int e1 = min(e0 + CHUNK, 2 * E);
    for (int i = threadIdx.x; i < nbuck; i += 256) hist[i] = 0;
    __syncthreads();
    for (int e = e0 + threadIdx.x; e < e1; e += 256) {
        int d = (e >= E) ? (N + dst1[e - E]) : dst0[e];
        atomicAdd(&hist[d >> BSHIFT], 1);
    }
    __syncthreads();
    for (int i = threadIdx.x; i < nbuck; i += 256) {
        int c = hist[i];
        if (c > 0) atomicAdd(&bcnt[i], c);
    }
}

__global__ void bscan(const int* __restrict__ bcnt, int* __restrict__ bbase,
                      int* __restrict__ bcursor, int* __restrict__ rowptr, int nbuck) {
    __shared__ int sm[1024];
    int t = threadIdx.x;
    int v = (t < nbuck) ? bcnt[t] : 0;
    sm[t] = v;
    __syncthreads();
    for (int off = 1; off < 1024; off <<= 1) {
        int a = (t >= off) ? sm[t - off] : 0;
        __syncthreads();
        sm[t] += a;
        __syncthreads();
    }
    if (t < nbuck) {
        int excl = sm[t] - v;
        bbase[t] = excl;
        bcursor[t] = excl;
        if (t == nbuck - 1) bbase[nbuck] = sm[t];
    }
    if (t == 0) rowptr[0] = 0;
}

__global__ void bucket_scatter(const int* __restrict__ src0, const int* __restrict__ dst0,
                               const int* __restrict__ src1, const int* __restrict__ dst1,
                               int* __restrict__ bcursor, int* __restrict__ ebuf,
                               int N, int E, int nbuck) {
    __shared__ int hist[1024];
    __shared__ int cur[1024];
    int e0 = blockIdx.x * CHUNK;
    int e1 = min(e0 + CHUNK, 2 * E);
    for (int i = threadIdx.x; i < nbuck; i += 256) hist[i] = 0;
    __syncthreads();
    for (int e = e0 + threadIdx.x; e < e1; e += 256) {
        int d = (e >= E) ? (N + dst1[e - E]) : dst0[e];
        atomicAdd(&hist[d >> BSHIFT], 1);
    }
    __syncthreads();
    for (int i = threadIdx.x; i < nbuck; i += 256) {
        int c = hist[i];
        cur[i] = (c > 0) ? atomicAdd(&bcursor[i], c) : 0;
    }
    __syncthreads();
    for (int e = e0 + threadIdx.x; e < e1; e += 256) {
        int s, d;
        if (e >= E) { s = N + src1[e - E]; d = N + dst1[e - E]; }
        else        { s = src0[e];         d = dst0[e]; }
        int b = d >> BSHIFT;
        int pos = atomicAdd(&cur[b], 1);
        ebuf[pos] = ((d & (BNODES - 1)) << 17) | s;
    }
}

__global__ void bucket_sort(const int* __restrict__ ebuf_in, const int* __restrict__ bbase,
                            int* __restrict__ ebuf_out, int* __restrict__ rowptr,
                            float* __restrict__ dinv, float* __restrict__ rsb, int n2) {
    __shared__ int hist[BNODES];
    __shared__ int scan[BNODES];
    __shared__ int cur[BNODES];
    int b = blockIdx.x;
    int node0 = b << BSHIFT;
    int beg = bbase[b];
    int end = bbase[b + 1];
    int t = threadIdx.x;
    if (t < BNODES) hist[t] = 0;
    __syncthreads();
    for (int e = beg + t; e < end; e += 256)
        atomicAdd(&hist[(unsigned)ebuf_in[e] >> 17], 1);
    __syncthreads();
    if (t < BNODES) scan[t] = hist[t];
    __syncthreads();
    #pragma unroll
    for (int off = 1; off < BNODES; off <<= 1) {
        int a = (t < BNODES && t >= off) ? scan[t - off] : 0;
        __syncthreads();
        if (t < BNODES) scan[t] += a;
        __syncthreads();
    }
    int nvalid = min(BNODES, n2 - node0);
    if (t < nvalid) {
        int d = hist[t];
        int incl = scan[t];
        rowptr[node0 + t + 1] = beg + incl;
        cur[t] = beg + incl - d;
        float df = (float)(d < 1 ? 1 : d);
        float sq = sqrtf(df);
        rsb[node0 + t] = sq;
        dinv[node0 + t] = 1.0f / sq;
    }
    __syncthreads();
    for (int e = beg + t; e < end; e += 256) {
        int p = ebuf_in[e];
        int pos = atomicAdd(&cur[(unsigned)p >> 17], 1);
        ebuf_out[pos] = (p & 0x1FFFF) << 6;
    }
}

// ---------------------------------------------------------------------------
// SpMM on pre-scaled bf16 features: Fout[u] = Fin[u] - dinv[u]^2 * sum Fin[src].
// One wave per node, lane = feature. 8 gathers (2B each) in flight; 128B
// per edge from L2/L3 instead of 256B.
// ---------------------------------------------------------------------------
__global__ void spmm_s(const u16* __restrict__ Fin, u16* __restrict__ Fout,
                       const int* __restrict__ rowptr, const int* __restrict__ epay,
                       const float* __restrict__ dinv, int n2) {
    int u = (blockIdx.x * blockDim.x + threadIdx.x) >> 6;
    int j = threadIdx.x & 63;
    if (u >= n2) return;
    int beg = rowptr[u];
    int end = rowptr[u + 1];
    const u16* base = Fin + j;
    float a0 = 0.f, a1 = 0.f, a2 = 0.f, a3 = 0.f;
    int e = beg;
    for (; e + 8 <= end; e += 8) {
        int o0 = epay[e + 0], o1 = epay[e + 1], o2 = epay[e + 2], o3 = epay[e + 3];
        int o4 = epay[e + 4], o5 = epay[e + 5], o6 = epay[e + 6], o7 = epay[e + 7];
        u16 v0 = base[o0], v1 = base[o1], v2 = base[o2], v3 = base[o3];
        u16 v4 = base[o4], v5 = base[o5], v6 = base[o6], v7 = base[o7];
        a0 += bf2f(v0); a1 += bf2f(v1); a2 += bf2f(v2); a3 += bf2f(v3);
        a0 += bf2f(v4); a1 += bf2f(v5); a2 += bf2f(v6); a3 += bf2f(v7);
    }
    for (; e + 4 <= end; e += 4) {
        u16 v0 = base[epay[e + 0]], v1 = base[epay[e + 1]];
        u16 v2 = base[epay[e + 2]], v3 = base[epay[e + 3]];
        a0 += bf2f(v0); a1 += bf2f(v1); a2 += bf2f(v2); a3 += bf2f(v3);
    }
    for (; e < end; e++) a0 += bf2f(base[epay[e]]);
    float acc = (a0 + a1) + (a2 + a3);
    float di = dinv[u];
    size_t gi = (size_t)u * 64 + j;
    Fout[gi] = f2bf(bf2f(Fin[gi]) - (di * di) * acc);
}

// ---------------------------------------------------------------------------
// MLP GEMM, both branches in one dispatch. LDS-staged W, 2 rows/thread.
// SCALE=false: fp32 out (hidden tmp). SCALE=true: bf16 out = leaky(y)*dinv.
// ---------------------------------------------------------------------------
template <int K, bool SCALE>
__global__ void gemm_mlp(const float* __restrict__ A0, const float* __restrict__ A1, int lda,
                         const float* __restrict__ Wg0, const float* __restrict__ Wg1,
                         const float* __restrict__ bias0, const float* __restrict__ bias1,
                         const float* __restrict__ dinv, void* __restrict__ out_,
                         int N, int GB) {
    __shared__ float Ws[K * 64];
    __shared__ float bs[64];
    int br = (blockIdx.x >= GB) ? 1 : 0;
    const float* Wg = br ? Wg1 : Wg0;
    const float* bias = br ? bias1 : bias0;
    for (int i = threadIdx.x; i < K * 16; i += 256)
        reinterpret_cast<float4*>(Ws)[i] = reinterpret_cast<const float4*>(Wg)[i];
    if (threadIdx.x < 64) bs[threadIdx.x] = bias[threadIdx.x];
    __syncthreads();

    int lane = threadIdx.x & 63;
    int c0 = (threadIdx.x >> 6) * 16;
    int bb = blockIdx.x - br * GB;
    int r0 = bb * 128 + lane;
    int r1 = r0 + 64;
    bool v0 = r0 < N, v1 = r1 < N;
    int r0c = v0 ? r0 : N - 1;
    int r1c = v1 ? r1 : N - 1;
    const float* A = br ? A1 : A0;

    float acc0[16], acc1[16];
    #pragma unroll
    for (int j = 0; j < 16; j++) { acc0[j] = bs[c0 + j]; acc1[j] = bs[c0 + j]; }

    const float4* a0p = reinterpret_cast<const float4*>(A + (size_t)r0c * lda);
    const float4* a1p = reinterpret_cast<const float4*>(A + (size_t)r1c * lda);
    #pragma unroll 1
    for (int k4 = 0; k4 < K / 4; k4++) {
        float4 a0 = a0p[k4];
        float4 a1 = a1p[k4];
        #pragma unroll
        for (int kk = 0; kk < 4; kk++) {
            float a0k = (kk == 0) ? a0.x : (kk == 1) ? a0.y : (kk == 2) ? a0.z : a0.w;
            float a1k = (kk == 0) ? a1.x : (kk == 1) ? a1.y : (kk == 2) ? a1.z : a1.w;
            const float4* wrow = reinterpret_cast<const float4*>(Ws + (k4 * 4 + kk) * 64 + c0);
            #pragma unroll
            for (int j4 = 0; j4 < 4; j4++) {
                float4 w = wrow[j4];
                acc0[j4 * 4 + 0] += a0k * w.x; acc0[j4 * 4 + 1] += a0k * w.y;
                acc0[j4 * 4 + 2] += a0k * w.z; acc0[j4 * 4 + 3] += a0k * w.w;
                acc1[j4 * 4 + 0] += a1k * w.x; acc1[j4 * 4 + 1] += a1k * w.y;
                acc1[j4 * 4 + 2] += a1k * w.z; acc1[j4 * 4 + 3] += a1k * w.w;
            }
        }
    }

    if (SCALE) {
        u16* out = (u16*)out_;
        float s0 = dinv[br * N + r0c];
        float s1 = dinv[br * N + r1c];
        if (v0) {
            u16* o = out + (size_t)(br * N + r0) * 64 + c0;
            #pragma unroll
            for (int j = 0; j < 16; j++) o[j] = f2bf(leaky_f(acc0[j]) * s0);
        }
        if (v1) {
            u16* o = out + (size_t)(br * N + r1) * 64 + c0;
            #pragma unroll
            for (int j = 0; j < 16; j++) o[j] = f2bf(leaky_f(acc1[j]) * s1);
        }
    } else {
        float* out = (float*)out_;
        if (v0) {
            float* o = out + (size_t)(br * N + r0) * 64 + c0;
            #pragma unroll
            for (int j = 0; j < 16; j++) o[j] = leaky_f(acc0[j]);
        }
        if (v1) {
            float* o = out + (size_t)(br * N + r1) * 64 + c0;
            #pragma unroll
            for (int j = 0; j < 16; j++) o[j] = leaky_f(acc1[j]);
        }
    }
}

// ---------------------------------------------------------------------------
// Final fused GEMM with branch fold: both halves share M, so
//   out = leaky( (rs0*A_h0 + rs1*A_h1) @ M + 2*b3 )
// -> combine rows at load time, HALF the FMAs. 1 row/thread, 64 rows/block
// (782 blocks = 3.05 blocks/CU at 48KB LDS). bf16 table loads via uint4.
// ---------------------------------------------------------------------------
__global__ void gemmF(const u16* __restrict__ Hs, const u16* __restrict__ F1s,
                      const u16* __restrict__ F2s, const float* __restrict__ rsb,
                      const float* __restrict__ Mg, const float* __restrict__ b3,
                      float* __restrict__ out, int N) {
    __shared__ float Ms[192 * 64];
    __shared__ float bs[64];
    for (int i = threadIdx.x; i < 192 * 16; i += 256)
        reinterpret_cast<float4*>(Ms)[i] = reinterpret_cast<const float4*>(Mg)[i];
    if (threadIdx.x < 64) bs[threadIdx.x] = 2.f * b3[threadIdx.x];
    __syncthreads();

    int lane = threadIdx.x & 63;
    int c0 = (threadIdx.x >> 6) * 16;
    int r = blockIdx.x * 64 + lane;
    bool valid = r < N;
    int rc = valid ? r : N - 1;
    float s0 = rsb[rc];
    float s1 = rsb[N + rc];

    float acc[16];
    #pragma unroll
    for (int j = 0; j < 16; j++) acc[j] = bs[c0 + j];

    #pragma unroll
    for (int pa = 0; pa < 3; pa++) {
        const u16* P = (pa == 0) ? Hs : (pa == 1) ? F1s : F2s;
        const uint4* p0 = reinterpret_cast<const uint4*>(P) + (size_t)rc * 8;
        const uint4* p1 = reinterpret_cast<const uint4*>(P) + ((size_t)N + rc) * 8;
        #pragma unroll 1
        for (int k8 = 0; k8 < 8; k8++) {
            uint4 x0 = p0[k8];
            uint4 x1 = p1[k8];
            float a[8];
            a[0] = s0 * bflo(x0.x) + s1 * bflo(x1.x);
            a[1] = s0 * bfhi(x0.x) + s1 * bfhi(x1.x);
            a[2] = s0 * bflo(x0.y) + s1 * bflo(x1.y);
            a[3] = s0 * bfhi(x0.y) + s1 * bfhi(x1.y);
            a[4] = s0 * bflo(x0.z) + s1 * bflo(x1.z);
            a[5] = s0 * bfhi(x0.z) + s1 * bfhi(x1.z);
            a[6] = s0 * bflo(x0.w) + s1 * bflo(x1.w);
            a[7] = s0 * bfhi(x0.w) + s1 * bfhi(x1.w);
            #pragma unroll
            for (int kk = 0; kk < 8; kk++) {
                const float4* wrow =
                    reinterpret_cast<const float4*>(Ms + (pa * 64 + k8 * 8 + kk) * 64 + c0);
                #pragma unroll
                for (int j4 = 0; j4 < 4; j4++) {
                    float4 w = wrow[j4];
                    acc[j4 * 4 + 0] += a[kk] * w.x;
                    acc[j4 * 4 + 1] += a[kk] * w.y;
                    acc[j4 * 4 + 2] += a[kk] * w.z;
                    acc[j4 * 4 + 3] += a[kk] * w.w;
                }
            }
        }
    }

    if (valid) {
        float* o = out + (size_t)r * 64 + c0;
        #pragma unroll
        for (int j = 0; j < 16; j++) o[j] = leaky_f(acc[j]);
    }
}

// ---------------------------------------------------------------------------
extern "C" void kernel_launch(void* const* d_in, const int* in_sizes, int n_in,
                              void* d_out, int out_size, void* d_ws, size_t ws_size,
                              hipStream_t stream) {
    const int N = in_sizes[0] / 128;
    const int E = in_sizes[2];
    const int N2 = 2 * N;
    const int NBUCK = (N2 + BNODES - 1) >> BSHIFT;

    const float* feat0 = (const float*)d_in[0];
    const float* feat1 = (const float*)d_in[1];
    const int*   src0  = (const int*)d_in[2];
    const int*   dst0  = (const int*)d_in[3];
    const int*   src1  = (const int*)d_in[4];
    const int*   dst1  = (const int*)d_in[5];
    const float* W1_0  = (const float*)d_in[6];
    const float* b1_0  = (const float*)d_in[7];
    const float* W2_0  = (const float*)d_in[8];
    const float* b2_0  = (const float*)d_in[9];
    const float* W1_1  = (const float*)d_in[10];
    const float* b1_1  = (const float*)d_in[11];
    const float* W2_1  = (const float*)d_in[12];
    const float* b2_1  = (const float*)d_in[13];
    const float* W3    = (const float*)d_in[14];
    const float* b3    = (const float*)d_in[15];
    float* out = (float*)d_out;

    char* p = (char*)d_ws;
    auto alloc = [&](size_t bytes) -> char* {
        char* r = p;
        p += (bytes + 255) & ~(size_t)255;
        return r;
    };
    float* Mcat    = (float*)alloc((size_t)192 * 64 * 4);
    u16*   Hs      = (u16*)alloc((size_t)N2 * 64 * 2);   // bf16: h * dinv
    u16*   F1s     = (u16*)alloc((size_t)N2 * 64 * 2);   // bf16: f1 * dinv
    u16*   F2s     = (u16*)alloc((size_t)N2 * 64 * 2);   // bf16: f2 * dinv
    float* tmp     = (float*)alloc((size_t)N2 * 64 * 4); // fp32 MLP hidden
    float* dinv    = (float*)alloc((size_t)N2 * 4);
    float* rsb     = (float*)alloc((size_t)N2 * 4);
    int*   rowptr  = (int*)alloc((size_t)(N2 + 1) * 4);
    int*   bcnt    = (int*)alloc((size_t)NBUCK * 4);
    int*   bbase   = (int*)alloc((size_t)(NBUCK + 1) * 4);
    int*   bcursor = (int*)alloc((size_t)NBUCK * 4);
    int*   ebuf1   = (int*)alloc((size_t)2 * E * 4);
    int*   ebuf2   = (int*)alloc((size_t)2 * E * 4);
    (void)ws_size; (void)n_in; (void)out_size;

    const int GB = (N + 127) / 128;
    const int ECH = (2 * E + CHUNK - 1) / CHUNK;

    compute_M<<<(192 * 64 + 255) / 256, 256, 0, stream>>>(W3, Mcat);

    // --- graph build: bucket counts -> scan -> clustered scatter -> local sort ---
    hipMemsetAsync(bcnt, 0, (size_t)NBUCK * 4, stream);
    bcount<<<ECH, 256, 0, stream>>>(dst0, dst1, bcnt, N, E, NBUCK);
    bscan<<<1, 1024, 0, stream>>>(bcnt, bbase, bcursor, rowptr, NBUCK);
    bucket_scatter<<<ECH, 256, 0, stream>>>(src0, dst0, src1, dst1, bcursor, ebuf1, N, E, NBUCK);
    bucket_sort<<<NBUCK, 256, 0, stream>>>(ebuf1, bbase, ebuf2, rowptr, dinv, rsb, N2);

    // --- MLP (both branches): tmp = leaky(X@W1+b1); Hs = bf16(leaky(tmp@W2+b2)*dinv) ---
    gemm_mlp<128, false><<<2 * GB, 256, 0, stream>>>(
        feat0, feat1, 128, W1_0, W1_1, b1_0, b1_1, dinv, tmp, N, GB);
    gemm_mlp<64, true><<<2 * GB, 256, 0, stream>>>(
        tmp, tmp + (size_t)N * 64, 64, W2_0, W2_1, b2_0, b2_1, dinv, Hs, N, GB);

    // --- polynomial propagation on scaled bf16 features (node-sorted CSR) ---
    spmm_s<<<(N2 * 64 + 255) / 256, 256, 0, stream>>>(Hs, F1s, rowptr, ebuf2, dinv, N2);
    spmm_s<<<(N2 * 64 + 255) / 256, 256, 0, stream>>>(F1s, F2s, rowptr, ebuf2, dinv, N2);

    // --- out = leaky( (rs0*A0 + rs1*A1) @ M + 2*b3 ), branch-folded ---
    gemmF<<<(N + 63) / 64, 256, 0, stream>>>(Hs, F1s, F2s, rsb, Mcat, b3, out, N);
}

// Round 8
// 257.335 us; speedup vs baseline: 6.2720x; 1.1036x over previous
//
#include <hip/hip_runtime.h>

#define LEAKY_SLOPE 0.01f
#define BSHIFT 7              // 128 nodes per bucket
#define BNODES 128
#define CHUNK 8192            // edges per chunked block

typedef unsigned short u16;
typedef short short8 __attribute__((ext_vector_type(8)));
typedef float f32x4 __attribute__((ext_vector_type(4)));

__device__ __forceinline__ float leaky_f(float x) { return x > 0.f ? x : LEAKY_SLOPE * x; }

__device__ __forceinline__ float bf2f(u16 b) {
    return __uint_as_float(((unsigned int)b) << 16);
}
__device__ __forceinline__ u16 f2bf(float f) {
    unsigned int u = __float_as_uint(f);
    return (u16)((u + 0x7FFFu + ((u >> 16) & 1u)) >> 16);  // RNE
}
__device__ __forceinline__ float bflo(unsigned int u) { return __uint_as_float(u << 16); }
__device__ __forceinline__ float bfhi(unsigned int u) { return __uint_as_float(u & 0xFFFF0000u); }
__device__ __forceinline__ unsigned int pack2bf(float lo, float hi) {
    return (unsigned int)f2bf(lo) | ((unsigned int)f2bf(hi) << 16);
}

union U16x8 { uint4 q; short8 s; };

// ---------------------------------------------------------------------------
// Combine THETAS (compile-time, D=2) with W3 (192x64), store TRANSPOSED bf16:
// Mt[c][k] = sum_t TH[t][k/64] * W3[...]  (so MFMA B-frag k-runs are contiguous)
// ---------------------------------------------------------------------------
__global__ void compute_M(const float* __restrict__ W3, u16* __restrict__ Mt) {
    int idx = blockIdx.x * blockDim.x + threadIdx.x;
    if (idx >= 192 * 64) return;
    int c = idx & 63;
    int r = (idx >> 6) & 63;
    int k = idx >> 12;  // 0..2
    const float TH[3][3] = {{3.f, -3.f, 0.75f},
                            {0.f,  3.f, -1.5f},
                            {0.f,  0.f, 0.75f}};
    float v = 0.f;
    #pragma unroll
    for (int t = 0; t < 3; t++) v += TH[t][k] * W3[(t * 64 + r) * 64 + c];
    Mt[c * 192 + k * 64 + r] = f2bf(v);
}

// ---------------------------------------------------------------------------
// Graph build (unchanged): bucket counts -> scan -> clustered scatter ->
// per-bucket local counting sort.
// ---------------------------------------------------------------------------
__global__ void bcount(const int* __restrict__ dst0, const int* __restrict__ dst1,
                       int* __restrict__ bcnt, int N, int E, int nbuck) {
    __shared__ int hist[1024];
    int e0 = blockIdx.x * CHUNK;
    int e1 = min(e0 + CHUNK, 2 * E);
    for (int i = threadIdx.x; i < nbuck; i += 256) hist[i] = 0;
    __syncthreads();
    for (int e = e0 + threadIdx.x; e < e1; e += 256) {
        int d = (e >= E) ? (N + dst1[e - E]) : dst0[e];
        atomicAdd(&hist[d >> BSHIFT], 1);
    }
    __syncthreads();
    for (int i = threadIdx.x; i < nbuck; i += 256) {
        int c = hist[i];
        if (c > 0) atomicAdd(&bcnt[i], c);
    }
}

__global__ void bscan(const int* __restrict__ bcnt, int* __restrict__ bbase,
                      int* __restrict__ bcursor, int* __restrict__ rowptr, int nbuck) {
    __shared__ int sm[1024];
    int t = threadIdx.x;
    int v = (t < nbuck) ? bcnt[t] : 0;
    sm[t] = v;
    __syncthreads();
    for (int off = 1; off < 1024; off <<= 1) {
        int a = (t >= off) ? sm[t - off] : 0;
        __syncthreads();
        sm[t] += a;
        __syncthreads();
    }
    if (t < nbuck) {
        int excl = sm[t] - v;
        bbase[t] = excl;
        bcursor[t] = excl;
        if (t == nbuck - 1) bbase[nbuck] = sm[t];
    }
    if (t == 0) rowptr[0] = 0;
}

__global__ void bucket_scatter(const int* __restrict__ src0, const int* __restrict__ dst0,
                               const int* __restrict__ src1, const int* __restrict__ dst1,
                               int* __restrict__ bcursor, int* __restrict__ ebuf,
                               int N, int E, int nbuck) {
    __shared__ int hist[1024];
    __shared__ int cur[1024];
    int e0 = blockIdx.x * CHUNK;
    int e1 = min(e0 + CHUNK, 2 * E);
    for (int i = threadIdx.x; i < nbuck; i += 256) hist[i] = 0;
    __syncthreads();
    for (int e = e0 + threadIdx.x; e < e1; e += 256) {
        int d = (e >= E) ? (N + dst1[e - E]) : dst0[e];
        atomicAdd(&hist[d >> BSHIFT], 1);
    }
    __syncthreads();
    for (int i = threadIdx.x; i < nbuck; i += 256) {
        int c = hist[i];
        cur[i] = (c > 0) ? atomicAdd(&bcursor[i], c) : 0;
    }
    __syncthreads();
    for (int e = e0 + threadIdx.x; e < e1; e += 256) {
        int s, d;
        if (e >= E) { s = N + src1[e - E]; d = N + dst1[e - E]; }
        else        { s = src0[e];         d = dst0[e]; }
        int b = d >> BSHIFT;
        int pos = atomicAdd(&cur[b], 1);
        ebuf[pos] = ((d & (BNODES - 1)) << 17) | s;
    }
}

__global__ void bucket_sort(const int* __restrict__ ebuf_in, const int* __restrict__ bbase,
                            int* __restrict__ ebuf_out, int* __restrict__ rowptr,
                            float* __restrict__ dinv, float* __restrict__ rsb, int n2) {
    __shared__ int hist[BNODES];
    __shared__ int scan[BNODES];
    __shared__ int cur[BNODES];
    int b = blockIdx.x;
    int node0 = b << BSHIFT;
    int beg = bbase[b];
    int end = bbase[b + 1];
    int t = threadIdx.x;
    if (t < BNODES) hist[t] = 0;
    __syncthreads();
    for (int e = beg + t; e < end; e += 256)
        atomicAdd(&hist[(unsigned)ebuf_in[e] >> 17], 1);
    __syncthreads();
    if (t < BNODES) scan[t] = hist[t];
    __syncthreads();
    #pragma unroll
    for (int off = 1; off < BNODES; off <<= 1) {
        int a = (t < BNODES && t >= off) ? scan[t - off] : 0;
        __syncthreads();
        if (t < BNODES) scan[t] += a;
        __syncthreads();
    }
    int nvalid = min(BNODES, n2 - node0);
    if (t < nvalid) {
        int d = hist[t];
        int incl = scan[t];
        rowptr[node0 + t + 1] = beg + incl;
        cur[t] = beg + incl - d;
        float df = (float)(d < 1 ? 1 : d);
        float sq = sqrtf(df);
        rsb[node0 + t] = sq;
        dinv[node0 + t] = 1.0f / sq;
    }
    __syncthreads();
    for (int e = beg + t; e < end; e += 256) {
        int p = ebuf_in[e];
        int pos = atomicAdd(&cur[(unsigned)p >> 17], 1);
        ebuf_out[pos] = (p & 0x1FFFF) << 6;
    }
}

// ---------------------------------------------------------------------------
// SpMM on pre-scaled bf16 features: Fout[u] = Fin[u] - dinv[u]^2 * sum Fin[src].
// One wave per node, lane = feature. 8 gathers in flight.
// ---------------------------------------------------------------------------
__global__ void spmm_s(const u16* __restrict__ Fin, u16* __restrict__ Fout,
                       const int* __restrict__ rowptr, const int* __restrict__ epay,
                       const float* __restrict__ dinv, int n2) {
    int u = (blockIdx.x * blockDim.x + threadIdx.x) >> 6;
    int j = threadIdx.x & 63;
    if (u >= n2) return;
    int beg = rowptr[u];
    int end = rowptr[u + 1];
    const u16* base = Fin + j;
    float a0 = 0.f, a1 = 0.f, a2 = 0.f, a3 = 0.f;
    int e = beg;
    for (; e + 8 <= end; e += 8) {
        int o0 = epay[e + 0], o1 = epay[e + 1], o2 = epay[e + 2], o3 = epay[e + 3];
        int o4 = epay[e + 4], o5 = epay[e + 5], o6 = epay[e + 6], o7 = epay[e + 7];
        u16 v0 = base[o0], v1 = base[o1], v2 = base[o2], v3 = base[o3];
        u16 v4 = base[o4], v5 = base[o5], v6 = base[o6], v7 = base[o7];
        a0 += bf2f(v0); a1 += bf2f(v1); a2 += bf2f(v2); a3 += bf2f(v3);
        a0 += bf2f(v4); a1 += bf2f(v5); a2 += bf2f(v6); a3 += bf2f(v7);
    }
    for (; e + 4 <= end; e += 4) {
        u16 v0 = base[epay[e + 0]], v1 = base[epay[e + 1]];
        u16 v2 = base[epay[e + 2]], v3 = base[epay[e + 3]];
        a0 += bf2f(v0); a1 += bf2f(v1); a2 += bf2f(v2); a3 += bf2f(v3);
    }
    for (; e < end; e++) a0 += bf2f(base[epay[e]]);
    float acc = (a0 + a1) + (a2 + a3);
    float di = dinv[u];
    size_t gi = (size_t)u * 64 + j;
    Fout[gi] = f2bf(bf2f(Fin[gi]) - (di * di) * acc);
}

// ---------------------------------------------------------------------------
// MLP GEMM (unchanged): LDS-staged W, 2 rows/thread, both branches.
// ---------------------------------------------------------------------------
template <int K, bool SCALE>
__global__ void gemm_mlp(const float* __restrict__ A0, const float* __restrict__ A1, int lda,
                         const float* __restrict__ Wg0, const float* __restrict__ Wg1,
                         const float* __restrict__ bias0, const float* __restrict__ bias1,
                         const float* __restrict__ dinv, void* __restrict__ out_,
                         int N, int GB) {
    __shared__ float Ws[K * 64];
    __shared__ float bs[64];
    int br = (blockIdx.x >= GB) ? 1 : 0;
    const float* Wg = br ? Wg1 : Wg0;
    const float* bias = br ? bias1 : bias0;
    for (int i = threadIdx.x; i < K * 16; i += 256)
        reinterpret_cast<float4*>(Ws)[i] = reinterpret_cast<const float4*>(Wg)[i];
    if (threadIdx.x < 64) bs[threadIdx.x] = bias[threadIdx.x];
    __syncthreads();

    int lane = threadIdx.x & 63;
    int c0 = (threadIdx.x >> 6) * 16;
    int bb = blockIdx.x - br * GB;
    int r0 = bb * 128 + lane;
    int r1 = r0 + 64;
    bool v0 = r0 < N, v1 = r1 < N;
    int r0c = v0 ? r0 : N - 1;
    int r1c = v1 ? r1 : N - 1;
    const float* A = br ? A1 : A0;

    float acc0[16], acc1[16];
    #pragma unroll
    for (int j = 0; j < 16; j++) { acc0[j] = bs[c0 + j]; acc1[j] = bs[c0 + j]; }

    const float4* a0p = reinterpret_cast<const float4*>(A + (size_t)r0c * lda);
    const float4* a1p = reinterpret_cast<const float4*>(A + (size_t)r1c * lda);
    #pragma unroll 1
    for (int k4 = 0; k4 < K / 4; k4++) {
        float4 a0 = a0p[k4];
        float4 a1 = a1p[k4];
        #pragma unroll
        for (int kk = 0; kk < 4; kk++) {
            float a0k = (kk == 0) ? a0.x : (kk == 1) ? a0.y : (kk == 2) ? a0.z : a0.w;
            float a1k = (kk == 0) ? a1.x : (kk == 1) ? a1.y : (kk == 2) ? a1.z : a1.w;
            const float4* wrow = reinterpret_cast<const float4*>(Ws + (k4 * 4 + kk) * 64 + c0);
            #pragma unroll
            for (int j4 = 0; j4 < 4; j4++) {
                float4 w = wrow[j4];
                acc0[j4 * 4 + 0] += a0k * w.x; acc0[j4 * 4 + 1] += a0k * w.y;
                acc0[j4 * 4 + 2] += a0k * w.z; acc0[j4 * 4 + 3] += a0k * w.w;
                acc1[j4 * 4 + 0] += a1k * w.x; acc1[j4 * 4 + 1] += a1k * w.y;
                acc1[j4 * 4 + 2] += a1k * w.z; acc1[j4 * 4 + 3] += a1k * w.w;
            }
        }
    }

    if (SCALE) {
        u16* out = (u16*)out_;
        float s0 = dinv[br * N + r0c];
        float s1 = dinv[br * N + r1c];
        if (v0) {
            u16* o = out + (size_t)(br * N + r0) * 64 + c0;
            #pragma unroll
            for (int j = 0; j < 16; j++) o[j] = f2bf(leaky_f(acc0[j]) * s0);
        }
        if (v1) {
            u16* o = out + (size_t)(br * N + r1) * 64 + c0;
            #pragma unroll
            for (int j = 0; j < 16; j++) o[j] = f2bf(leaky_f(acc1[j]) * s1);
        }
    } else {
        float* out = (float*)out_;
        if (v0) {
            float* o = out + (size_t)(br * N + r0) * 64 + c0;
            #pragma unroll
            for (int j = 0; j < 16; j++) o[j] = leaky_f(acc0[j]);
        }
        if (v1) {
            float* o = out + (size_t)(br * N + r1) * 64 + c0;
            #pragma unroll
            for (int j = 0; j < 16; j++) o[j] = leaky_f(acc1[j]);
        }
    }
}

// ---------------------------------------------------------------------------
// Final GEMM via MFMA, no LDS. out = leaky( (rs0*A_h0 + rs1*A_h1) @ M + 2*b3 ).
// Wave handles 16 rows x 64 cols. B (= M, transposed bf16 Mt[64][192]) lives
// in 24 short8 frags (~96 VGPRs, loaded once). A frags built in-register:
// fp32 branch-fold of the 6 bf16 table reads -> bf16.
// MFMA 16x16x32: A row=lane&15, k=(lane>>4)*8+e; B col=lane&15, same k;
// D col=lane&15, row=(lane>>4)*4+reg (verified m89 layout).
// ---------------------------------------------------------------------------
__global__ void gemmF_mfma(const u16* __restrict__ Hs, const u16* __restrict__ F1s,
                           const u16* __restrict__ F2s, const float* __restrict__ rsb,
                           const u16* __restrict__ Mt, const float* __restrict__ b3,
                           float* __restrict__ out, int N) {
    int lane = threadIdx.x & 63;
    int wv = threadIdx.x >> 6;          // wave 0..3
    int r0 = blockIdx.x * 64 + wv * 16; // this wave's 16 rows
    int j = lane & 15;
    int kh = lane >> 4;                 // 0..3

    // --- B fragments: Mt[nt*16+j][ks*32 + kh*8 .. +7] ---
    short8 bfrag[6][4];
    #pragma unroll
    for (int nt = 0; nt < 4; nt++) {
        const u16* mrow = Mt + (size_t)(nt * 16 + j) * 192 + kh * 8;
        #pragma unroll
        for (int ks = 0; ks < 6; ks++) {
            U16x8 u;
            u.q = *reinterpret_cast<const uint4*>(mrow + ks * 32);
            bfrag[ks][nt] = u.s;
        }
    }

    // --- A fragments: branch-folded rows, bf16 ---
    int rr = r0 + j;                    // A-frag row = lane&15
    int rc = (rr < N) ? rr : N - 1;
    float s0 = rsb[rc];
    float s1 = rsb[N + rc];

    short8 afrag[6];
    #pragma unroll
    for (int ks = 0; ks < 6; ks++) {
        int pa = ks >> 1;
        const u16* P = (pa == 0) ? Hs : (pa == 1) ? F1s : F2s;
        int koff = (ks & 1) * 32 + kh * 8;
        uint4 x0 = *reinterpret_cast<const uint4*>(P + (size_t)rc * 64 + koff);
        uint4 x1 = *reinterpret_cast<const uint4*>(P + ((size_t)N + rc) * 64 + koff);
        U16x8 u;
        u.q.x = pack2bf(s0 * bflo(x0.x) + s1 * bflo(x1.x),
                        s0 * bfhi(x0.x) + s1 * bfhi(x1.x));
        u.q.y = pack2bf(s0 * bflo(x0.y) + s1 * bflo(x1.y),
                        s0 * bfhi(x0.y) + s1 * bfhi(x1.y));
        u.q.z = pack2bf(s0 * bflo(x0.z) + s1 * bflo(x1.z),
                        s0 * bfhi(x0.z) + s1 * bfhi(x1.z));
        u.q.w = pack2bf(s0 * bflo(x0.w) + s1 * bflo(x1.w),
                        s0 * bfhi(x0.w) + s1 * bfhi(x1.w));
        afrag[ks] = u.s;
    }

    // --- accumulate: acc[nt] over 6 k-steps ---
    f32x4 acc[4];
    #pragma unroll
    for (int nt = 0; nt < 4; nt++) {
        float bv = 2.f * b3[nt * 16 + j];
        acc[nt] = (f32x4){bv, bv, bv, bv};
    }
    #pragma unroll
    for (int nt = 0; nt < 4; nt++) {
        #pragma unroll
        for (int ks = 0; ks < 6; ks++) {
            acc[nt] = __builtin_amdgcn_mfma_f32_16x16x32_bf16(
                afrag[ks], bfrag[ks][nt], acc[nt], 0, 0, 0);
        }
    }

    // --- store: row = r0 + kh*4 + reg, col = nt*16 + j ---
    int rbase = r0 + kh * 4;
    #pragma unroll
    for (int reg = 0; reg < 4; reg++) {
        int row = rbase + reg;
        if (row < N) {
            float* o = out + (size_t)row * 64 + j;
            #pragma unroll
            for (int nt = 0; nt < 4; nt++)
                o[nt * 16] = leaky_f(acc[nt][reg]);
        }
    }
}

// ---------------------------------------------------------------------------
extern "C" void kernel_launch(void* const* d_in, const int* in_sizes, int n_in,
                              void* d_out, int out_size, void* d_ws, size_t ws_size,
                              hipStream_t stream) {
    const int N = in_sizes[0] / 128;
    const int E = in_sizes[2];
    const int N2 = 2 * N;
    const int NBUCK = (N2 + BNODES - 1) >> BSHIFT;

    const float* feat0 = (const float*)d_in[0];
    const float* feat1 = (const float*)d_in[1];
    const int*   src0  = (const int*)d_in[2];
    const int*   dst0  = (const int*)d_in[3];
    const int*   src1  = (const int*)d_in[4];
    const int*   dst1  = (const int*)d_in[5];
    const float* W1_0  = (const float*)d_in[6];
    const float* b1_0  = (const float*)d_in[7];
    const float* W2_0  = (const float*)d_in[8];
    const float* b2_0  = (const float*)d_in[9];
    const float* W1_1  = (const float*)d_in[10];
    const float* b1_1  = (const float*)d_in[11];
    const float* W2_1  = (const float*)d_in[12];
    const float* b2_1  = (const float*)d_in[13];
    const float* W3    = (const float*)d_in[14];
    const float* b3    = (const float*)d_in[15];
    float* out = (float*)d_out;

    char* p = (char*)d_ws;
    auto alloc = [&](size_t bytes) -> char* {
        char* r = p;
        p += (bytes + 255) & ~(size_t)255;
        return r;
    };
    u16*   Mt      = (u16*)alloc((size_t)64 * 192 * 2);  // bf16, transposed
    u16*   Hs      = (u16*)alloc((size_t)N2 * 64 * 2);   // bf16: h * dinv
    u16*   F1s     = (u16*)alloc((size_t)N2 * 64 * 2);   // bf16: f1 * dinv
    u16*   F2s     = (u16*)alloc((size_t)N2 * 64 * 2);   // bf16: f2 * dinv
    float* tmp     = (float*)alloc((size_t)N2 * 64 * 4); // fp32 MLP hidden
    float* dinv    = (float*)alloc((size_t)N2 * 4);
    float* rsb     = (float*)alloc((size_t)N2 * 4);
    int*   rowptr  = (int*)alloc((size_t)(N2 + 1) * 4);
    int*   bcnt    = (int*)alloc((size_t)NBUCK * 4);
    int*   bbase   = (int*)alloc((size_t)(NBUCK + 1) * 4);
    int*   bcursor = (int*)alloc((size_t)NBUCK * 4);
    int*   ebuf1   = (int*)alloc((size_t)2 * E * 4);
    int*   ebuf2   = (int*)alloc((size_t)2 * E * 4);
    (void)ws_size; (void)n_in; (void)out_size;

    const int GB = (N + 127) / 128;
    const int ECH = (2 * E + CHUNK - 1) / CHUNK;

    compute_M<<<(192 * 64 + 255) / 256, 256, 0, stream>>>(W3, Mt);

    // --- graph build ---
    hipMemsetAsync(bcnt, 0, (size_t)NBUCK * 4, stream);
    bcount<<<ECH, 256, 0, stream>>>(dst0, dst1, bcnt, N, E, NBUCK);
    bscan<<<1, 1024, 0, stream>>>(bcnt, bbase, bcursor, rowptr, NBUCK);
    bucket_scatter<<<ECH, 256, 0, stream>>>(src0, dst0, src1, dst1, bcursor, ebuf1, N, E, NBUCK);
    bucket_sort<<<NBUCK, 256, 0, stream>>>(ebuf1, bbase, ebuf2, rowptr, dinv, rsb, N2);

    // --- MLP (both branches) ---
    gemm_mlp<128, false><<<2 * GB, 256, 0, stream>>>(
        feat0, feat1, 128, W1_0, W1_1, b1_0, b1_1, dinv, tmp, N, GB);
    gemm_mlp<64, true><<<2 * GB, 256, 0, stream>>>(
        tmp, tmp + (size_t)N * 64, 64, W2_0, W2_1, b2_0, b2_1, dinv, Hs, N, GB);

    // --- polynomial propagation (bf16, node-sorted CSR) ---
    spmm_s<<<(N2 * 64 + 255) / 256, 256, 0, stream>>>(Hs, F1s, rowptr, ebuf2, dinv, N2);
    spmm_s<<<(N2 * 64 + 255) / 256, 256, 0, stream>>>(F1s, F2s, rowptr, ebuf2, dinv, N2);

    // --- final GEMM via MFMA, branch-folded ---
    gemmF_mfma<<<(N + 63) / 64, 256, 0, stream>>>(Hs, F1s, F2s, rsb, Mt, b3, out, N);
}

// Round 9
// 202.799 us; speedup vs baseline: 7.9586x; 1.2689x over previous
//
#include <hip/hip_runtime.h>

#define LEAKY_SLOPE 0.01f
#define BSHIFT 7              // 128 nodes per bucket
#define BNODES 128
#define CHUNK 8192            // edges per chunked block

typedef unsigned short u16;
typedef short short8 __attribute__((ext_vector_type(8)));
typedef float f32x4 __attribute__((ext_vector_type(4)));

__device__ __forceinline__ float leaky_f(float x) { return x > 0.f ? x : LEAKY_SLOPE * x; }

__device__ __forceinline__ float bf2f(u16 b) {
    return __uint_as_float(((unsigned int)b) << 16);
}
__device__ __forceinline__ u16 f2bf(float f) {
    unsigned int u = __float_as_uint(f);
    return (u16)((u + 0x7FFFu + ((u >> 16) & 1u)) >> 16);  // RNE
}
__device__ __forceinline__ float bflo(unsigned int u) { return __uint_as_float(u << 16); }
__device__ __forceinline__ float bfhi(unsigned int u) { return __uint_as_float(u & 0xFFFF0000u); }
__device__ __forceinline__ unsigned int pack2bf(float lo, float hi) {
    return (unsigned int)f2bf(lo) | ((unsigned int)f2bf(hi) << 16);
}

union U16x8 { uint4 q; short8 s; };

// ---------------------------------------------------------------------------
// Prep: Mt = (THETA ⊗ W3) transposed bf16 [64][192];
//       W1t/W2t = per-branch transposed bf16 weights [c][k].
// ---------------------------------------------------------------------------
__global__ void compute_M(const float* __restrict__ W3, u16* __restrict__ Mt) {
    int idx = blockIdx.x * blockDim.x + threadIdx.x;
    if (idx >= 192 * 64) return;
    int c = idx & 63;
    int r = (idx >> 6) & 63;
    int k = idx >> 12;  // 0..2
    const float TH[3][3] = {{3.f, -3.f, 0.75f},
                            {0.f,  3.f, -1.5f},
                            {0.f,  0.f, 0.75f}};
    float v = 0.f;
    #pragma unroll
    for (int t = 0; t < 3; t++) v += TH[t][k] * W3[(t * 64 + r) * 64 + c];
    Mt[c * 192 + k * 64 + r] = f2bf(v);
}

__global__ void prep_w(const float* __restrict__ W1_0, const float* __restrict__ W1_1,
                       const float* __restrict__ W2_0, const float* __restrict__ W2_1,
                       u16* __restrict__ W1t, u16* __restrict__ W2t) {
    int idx = blockIdx.x * blockDim.x + threadIdx.x;
    if (idx < 2 * 64 * 128) {           // W1t[br][c][k], W1 is [k][c] (128x64)
        int br = idx >> 13;
        int c = (idx >> 7) & 63;
        int k = idx & 127;
        const float* W = br ? W1_1 : W1_0;
        W1t[idx] = f2bf(W[k * 64 + c]);
    }
    if (idx < 2 * 64 * 64) {            // W2t[br][c][k], W2 is [k][c] (64x64)
        int br = idx >> 12;
        int c = (idx >> 6) & 63;
        int k = idx & 63;
        const float* W = br ? W2_1 : W2_0;
        W2t[idx] = f2bf(W[k * 64 + c]);
    }
}

// ---------------------------------------------------------------------------
// Graph build (unchanged): bucket counts -> scan -> clustered scatter ->
// per-bucket local counting sort.
// ---------------------------------------------------------------------------
__global__ void bcount(const int* __restrict__ dst0, const int* __restrict__ dst1,
                       int* __restrict__ bcnt, int N, int E, int nbuck) {
    __shared__ int hist[1024];
    int e0 = blockIdx.x * CHUNK;
    int e1 = min(e0 + CHUNK, 2 * E);
    for (int i = threadIdx.x; i < nbuck; i += 256) hist[i] = 0;
    __syncthreads();
    for (int e = e0 + threadIdx.x; e < e1; e += 256) {
        int d = (e >= E) ? (N + dst1[e - E]) : dst0[e];
        atomicAdd(&hist[d >> BSHIFT], 1);
    }
    __syncthreads();
    for (int i = threadIdx.x; i < nbuck; i += 256) {
        int c = hist[i];
        if (c > 0) atomicAdd(&bcnt[i], c);
    }
}

__global__ void bscan(const int* __restrict__ bcnt, int* __restrict__ bbase,
                      int* __restrict__ bcursor, int* __restrict__ rowptr, int nbuck) {
    __shared__ int sm[1024];
    int t = threadIdx.x;
    int v = (t < nbuck) ? bcnt[t] : 0;
    sm[t] = v;
    __syncthreads();
    for (int off = 1; off < 1024; off <<= 1) {
        int a = (t >= off) ? sm[t - off] : 0;
        __syncthreads();
        sm[t] += a;
        __syncthreads();
    }
    if (t < nbuck) {
        int excl = sm[t] - v;
        bbase[t] = excl;
        bcursor[t] = excl;
        if (t == nbuck - 1) bbase[nbuck] = sm[t];
    }
    if (t == 0) rowptr[0] = 0;
}

__global__ void bucket_scatter(const int* __restrict__ src0, const int* __restrict__ dst0,
                               const int* __restrict__ src1, const int* __restrict__ dst1,
                               int* __restrict__ bcursor, int* __restrict__ ebuf,
                               int N, int E, int nbuck) {
    __shared__ int hist[1024];
    __shared__ int cur[1024];
    int e0 = blockIdx.x * CHUNK;
    int e1 = min(e0 + CHUNK, 2 * E);
    for (int i = threadIdx.x; i < nbuck; i += 256) hist[i] = 0;
    __syncthreads();
    for (int e = e0 + threadIdx.x; e < e1; e += 256) {
        int d = (e >= E) ? (N + dst1[e - E]) : dst0[e];
        atomicAdd(&hist[d >> BSHIFT], 1);
    }
    __syncthreads();
    for (int i = threadIdx.x; i < nbuck; i += 256) {
        int c = hist[i];
        cur[i] = (c > 0) ? atomicAdd(&bcursor[i], c) : 0;
    }
    __syncthreads();
    for (int e = e0 + threadIdx.x; e < e1; e += 256) {
        int s, d;
        if (e >= E) { s = N + src1[e - E]; d = N + dst1[e - E]; }
        else        { s = src0[e];         d = dst0[e]; }
        int b = d >> BSHIFT;
        int pos = atomicAdd(&cur[b], 1);
        ebuf[pos] = ((d & (BNODES - 1)) << 17) | s;
    }
}

__global__ void bucket_sort(const int* __restrict__ ebuf_in, const int* __restrict__ bbase,
                            int* __restrict__ ebuf_out, int* __restrict__ rowptr,
                            float* __restrict__ dinv, float* __restrict__ rsb, int n2) {
    __shared__ int hist[BNODES];
    __shared__ int scan[BNODES];
    __shared__ int cur[BNODES];
    int b = blockIdx.x;
    int node0 = b << BSHIFT;
    int beg = bbase[b];
    int end = bbase[b + 1];
    int t = threadIdx.x;
    if (t < BNODES) hist[t] = 0;
    __syncthreads();
    for (int e = beg + t; e < end; e += 256)
        atomicAdd(&hist[(unsigned)ebuf_in[e] >> 17], 1);
    __syncthreads();
    if (t < BNODES) scan[t] = hist[t];
    __syncthreads();
    #pragma unroll
    for (int off = 1; off < BNODES; off <<= 1) {
        int a = (t < BNODES && t >= off) ? scan[t - off] : 0;
        __syncthreads();
        if (t < BNODES) scan[t] += a;
        __syncthreads();
    }
    int nvalid = min(BNODES, n2 - node0);
    if (t < nvalid) {
        int d = hist[t];
        int incl = scan[t];
        rowptr[node0 + t + 1] = beg + incl;
        cur[t] = beg + incl - d;
        float df = (float)(d < 1 ? 1 : d);
        float sq = sqrtf(df);
        rsb[node0 + t] = sq;
        dinv[node0 + t] = 1.0f / sq;
    }
    __syncthreads();
    for (int e = beg + t; e < end; e += 256) {
        int p = ebuf_in[e];
        int pos = atomicAdd(&cur[(unsigned)p >> 17], 1);
        ebuf_out[pos] = (p & 0x1FFFF) << 6;
    }
}

// ---------------------------------------------------------------------------
// SpMM on pre-scaled bf16 features: Fout[u] = Fin[u] - dinv[u]^2 * sum Fin[src].
// One wave per node, lane = feature. readfirstlane forces beg/end (and hence
// epay offsets) into SGPRs -> s_load for offsets + saddr-form gathers,
// removing per-edge per-lane address VALU.
// ---------------------------------------------------------------------------
__global__ void spmm_s(const u16* __restrict__ Fin, u16* __restrict__ Fout,
                       const int* __restrict__ rowptr, const int* __restrict__ epay,
                       const float* __restrict__ dinv, int n2) {
    int u = (blockIdx.x * blockDim.x + threadIdx.x) >> 6;
    int j = threadIdx.x & 63;
    if (u >= n2) return;
    int beg = __builtin_amdgcn_readfirstlane(rowptr[u]);
    int end = __builtin_amdgcn_readfirstlane(rowptr[u + 1]);
    const u16* base = Fin + j;
    float a0 = 0.f, a1 = 0.f, a2 = 0.f, a3 = 0.f;
    int e = beg;
    for (; e + 8 <= end; e += 8) {
        int o0 = epay[e + 0], o1 = epay[e + 1], o2 = epay[e + 2], o3 = epay[e + 3];
        int o4 = epay[e + 4], o5 = epay[e + 5], o6 = epay[e + 6], o7 = epay[e + 7];
        u16 v0 = base[o0], v1 = base[o1], v2 = base[o2], v3 = base[o3];
        u16 v4 = base[o4], v5 = base[o5], v6 = base[o6], v7 = base[o7];
        a0 += bf2f(v0); a1 += bf2f(v1); a2 += bf2f(v2); a3 += bf2f(v3);
        a0 += bf2f(v4); a1 += bf2f(v5); a2 += bf2f(v6); a3 += bf2f(v7);
    }
    for (; e + 4 <= end; e += 4) {
        u16 v0 = base[epay[e + 0]], v1 = base[epay[e + 1]];
        u16 v2 = base[epay[e + 2]], v3 = base[epay[e + 3]];
        a0 += bf2f(v0); a1 += bf2f(v1); a2 += bf2f(v2); a3 += bf2f(v3);
    }
    for (; e < end; e++) a0 += bf2f(base[epay[e]]);
    float acc = (a0 + a1) + (a2 + a3);
    float di = dinv[u];
    size_t gi = (size_t)u * 64 + j;
    Fout[gi] = f2bf(bf2f(Fin[gi]) - (di * di) * acc);
}

// ---------------------------------------------------------------------------
// Fused 2-layer MLP via MFMA: Hs = bf16( leaky(leaky(X@W1+b1)@W2+b2) * dinv ).
// Per wave: 16 rows. Layer-1 A-frags cast fp32->bf16 in-register; hidden
// 16x64 tile goes through XOR-swizzled LDS (G4: 128B rows conflict) to
// re-fragment for layer 2. No HBM intermediate.
// MFMA 16x16x32 layouts (HW-verified by round-8 gemmF_mfma):
//   A: row=lane&15, k=(lane>>4)*8+e;  B: col=lane&15, same k;
//   C/D: col=lane&15, row=(lane>>4)*4+reg.
// ---------------------------------------------------------------------------
__global__ void mlp_mfma(const float* __restrict__ feat0, const float* __restrict__ feat1,
                         const u16* __restrict__ W1t, const u16* __restrict__ W2t,
                         const float* __restrict__ b1_0, const float* __restrict__ b1_1,
                         const float* __restrict__ b2_0, const float* __restrict__ b2_1,
                         const float* __restrict__ dinv, u16* __restrict__ Hs,
                         int N, int GB) {
    __shared__ u16 tls[4][16 * 64];     // per-wave 2KB, swizzled
    int br = (blockIdx.x >= GB) ? 1 : 0;
    int bb = blockIdx.x - br * GB;
    int lane = threadIdx.x & 63;
    int wv = threadIdx.x >> 6;
    int j = lane & 15;
    int kh = lane >> 4;
    int r0 = bb * 64 + wv * 16;
    const float* feat = br ? feat1 : feat0;
    const float* b1 = br ? b1_1 : b1_0;
    const float* b2 = br ? b2_1 : b2_0;
    const u16* w1t = W1t + br * 64 * 128;
    const u16* w2t = W2t + br * 64 * 64;

    int rr = r0 + j;
    int rc = (rr < N) ? rr : N - 1;

    // ---- layer 1: 16x128 @ 128x64 ----
    f32x4 acc[4];
    #pragma unroll
    for (int nt = 0; nt < 4; nt++) acc[nt] = (f32x4){0.f, 0.f, 0.f, 0.f};

    #pragma unroll
    for (int ks = 0; ks < 4; ks++) {
        const float* xp = feat + (size_t)rc * 128 + ks * 32 + kh * 8;
        float4 xa = *reinterpret_cast<const float4*>(xp);
        float4 xb = *reinterpret_cast<const float4*>(xp + 4);
        U16x8 ua;
        ua.q.x = pack2bf(xa.x, xa.y);
        ua.q.y = pack2bf(xa.z, xa.w);
        ua.q.z = pack2bf(xb.x, xb.y);
        ua.q.w = pack2bf(xb.z, xb.w);
        #pragma unroll
        for (int nt = 0; nt < 4; nt++) {
            U16x8 ub;
            ub.q = *reinterpret_cast<const uint4*>(w1t + (nt * 16 + j) * 128 + ks * 32 + kh * 8);
            acc[nt] = __builtin_amdgcn_mfma_f32_16x16x32_bf16(ua.s, ub.s, acc[nt], 0, 0, 0);
        }
    }

    // bias + leaky -> swizzled LDS (row-major [16][64] bf16, byte ^= (row&7)<<4)
    char* tl = reinterpret_cast<char*>(tls[wv]);
    #pragma unroll
    for (int nt = 0; nt < 4; nt++) {
        float bv = b1[nt * 16 + j];
        #pragma unroll
        for (int reg = 0; reg < 4; reg++) {
            int row = kh * 4 + reg;
            int byte = (row * 128 + (nt * 16 + j) * 2) ^ ((row & 7) << 4);
            *reinterpret_cast<u16*>(tl + byte) = f2bf(leaky_f(acc[nt][reg] + bv));
        }
    }
    __syncthreads();

    // ---- layer 2: 16x64 @ 64x64 ----
    f32x4 acc2[4];
    #pragma unroll
    for (int nt = 0; nt < 4; nt++) acc2[nt] = (f32x4){0.f, 0.f, 0.f, 0.f};
    #pragma unroll
    for (int ks = 0; ks < 2; ks++) {
        int byte = (j * 128 + (ks * 32 + kh * 8) * 2) ^ ((j & 7) << 4);
        U16x8 ua;
        ua.q = *reinterpret_cast<const uint4*>(tl + byte);
        #pragma unroll
        for (int nt = 0; nt < 4; nt++) {
            U16x8 ub;
            ub.q = *reinterpret_cast<const uint4*>(w2t + (nt * 16 + j) * 64 + ks * 32 + kh * 8);
            acc2[nt] = __builtin_amdgcn_mfma_f32_16x16x32_bf16(ua.s, ub.s, acc2[nt], 0, 0, 0);
        }
    }

    // epilogue: Hs[row][col] = bf16(leaky(acc2 + b2[col]) * dinv[row])
    int rowbase = r0 + kh * 4;
    #pragma unroll
    for (int reg = 0; reg < 4; reg++) {
        int row = rowbase + reg;
        if (row < N) {
            float di = dinv[br * N + row];
            u16* o = Hs + (size_t)(br * N + row) * 64 + j;
            #pragma unroll
            for (int nt = 0; nt < 4; nt++)
                o[nt * 16] = f2bf(leaky_f(acc2[nt][reg] + b2[nt * 16 + j]) * di);
        }
    }
}

// ---------------------------------------------------------------------------
// Final GEMM via MFMA (unchanged from round 8).
// ---------------------------------------------------------------------------
__global__ void gemmF_mfma(const u16* __restrict__ Hs, const u16* __restrict__ F1s,
                           const u16* __restrict__ F2s, const float* __restrict__ rsb,
                           const u16* __restrict__ Mt, const float* __restrict__ b3,
                           float* __restrict__ out, int N) {
    int lane = threadIdx.x & 63;
    int wv = threadIdx.x >> 6;
    int r0 = blockIdx.x * 64 + wv * 16;
    int j = lane & 15;
    int kh = lane >> 4;

    short8 bfrag[6][4];
    #pragma unroll
    for (int nt = 0; nt < 4; nt++) {
        const u16* mrow = Mt + (size_t)(nt * 16 + j) * 192 + kh * 8;
        #pragma unroll
        for (int ks = 0; ks < 6; ks++) {
            U16x8 u;
            u.q = *reinterpret_cast<const uint4*>(mrow + ks * 32);
            bfrag[ks][nt] = u.s;
        }
    }

    int rr = r0 + j;
    int rc = (rr < N) ? rr : N - 1;
    float s0 = rsb[rc];
    float s1 = rsb[N + rc];

    short8 afrag[6];
    #pragma unroll
    for (int ks = 0; ks < 6; ks++) {
        int pa = ks >> 1;
        const u16* P = (pa == 0) ? Hs : (pa == 1) ? F1s : F2s;
        int koff = (ks & 1) * 32 + kh * 8;
        uint4 x0 = *reinterpret_cast<const uint4*>(P + (size_t)rc * 64 + koff);
        uint4 x1 = *reinterpret_cast<const uint4*>(P + ((size_t)N + rc) * 64 + koff);
        U16x8 u;
        u.q.x = pack2bf(s0 * bflo(x0.x) + s1 * bflo(x1.x),
                        s0 * bfhi(x0.x) + s1 * bfhi(x1.x));
        u.q.y = pack2bf(s0 * bflo(x0.y) + s1 * bflo(x1.y),
                        s0 * bfhi(x0.y) + s1 * bfhi(x1.y));
        u.q.z = pack2bf(s0 * bflo(x0.z) + s1 * bflo(x1.z),
                        s0 * bfhi(x0.z) + s1 * bfhi(x1.z));
        u.q.w = pack2bf(s0 * bflo(x0.w) + s1 * bflo(x1.w),
                        s0 * bfhi(x0.w) + s1 * bfhi(x1.w));
        afrag[ks] = u.s;
    }

    f32x4 acc[4];
    #pragma unroll
    for (int nt = 0; nt < 4; nt++) {
        float bv = 2.f * b3[nt * 16 + j];
        acc[nt] = (f32x4){bv, bv, bv, bv};
    }
    #pragma unroll
    for (int nt = 0; nt < 4; nt++) {
        #pragma unroll
        for (int ks = 0; ks < 6; ks++) {
            acc[nt] = __builtin_amdgcn_mfma_f32_16x16x32_bf16(
                afrag[ks], bfrag[ks][nt], acc[nt], 0, 0, 0);
        }
    }

    int rbase = r0 + kh * 4;
    #pragma unroll
    for (int reg = 0; reg < 4; reg++) {
        int row = rbase + reg;
        if (row < N) {
            float* o = out + (size_t)row * 64 + j;
            #pragma unroll
            for (int nt = 0; nt < 4; nt++)
                o[nt * 16] = leaky_f(acc[nt][reg]);
        }
    }
}

// ---------------------------------------------------------------------------
extern "C" void kernel_launch(void* const* d_in, const int* in_sizes, int n_in,
                              void* d_out, int out_size, void* d_ws, size_t ws_size,
                              hipStream_t stream) {
    const int N = in_sizes[0] / 128;
    const int E = in_sizes[2];
    const int N2 = 2 * N;
    const int NBUCK = (N2 + BNODES - 1) >> BSHIFT;

    const float* feat0 = (const float*)d_in[0];
    const float* feat1 = (const float*)d_in[1];
    const int*   src0  = (const int*)d_in[2];
    const int*   dst0  = (const int*)d_in[3];
    const int*   src1  = (const int*)d_in[4];
    const int*   dst1  = (const int*)d_in[5];
    const float* W1_0  = (const float*)d_in[6];
    const float* b1_0  = (const float*)d_in[7];
    const float* W2_0  = (const float*)d_in[8];
    const float* b2_0  = (const float*)d_in[9];
    const float* W1_1  = (const float*)d_in[10];
    const float* b1_1  = (const float*)d_in[11];
    const float* W2_1  = (const float*)d_in[12];
    const float* b2_1  = (const float*)d_in[13];
    const float* W3    = (const float*)d_in[14];
    const float* b3    = (const float*)d_in[15];
    float* out = (float*)d_out;

    char* p = (char*)d_ws;
    auto alloc = [&](size_t bytes) -> char* {
        char* r = p;
        p += (bytes + 255) & ~(size_t)255;
        return r;
    };
    u16*   Mt      = (u16*)alloc((size_t)64 * 192 * 2);  // bf16, transposed
    u16*   W1t     = (u16*)alloc((size_t)2 * 64 * 128 * 2);
    u16*   W2t     = (u16*)alloc((size_t)2 * 64 * 64 * 2);
    u16*   Hs      = (u16*)alloc((size_t)N2 * 64 * 2);   // bf16: h * dinv
    u16*   F1s     = (u16*)alloc((size_t)N2 * 64 * 2);   // bf16: f1 * dinv
    u16*   F2s     = (u16*)alloc((size_t)N2 * 64 * 2);   // bf16: f2 * dinv
    float* dinv    = (float*)alloc((size_t)N2 * 4);
    float* rsb     = (float*)alloc((size_t)N2 * 4);
    int*   rowptr  = (int*)alloc((size_t)(N2 + 1) * 4);
    int*   bcnt    = (int*)alloc((size_t)NBUCK * 4);
    int*   bbase   = (int*)alloc((size_t)(NBUCK + 1) * 4);
    int*   bcursor = (int*)alloc((size_t)NBUCK * 4);
    int*   ebuf1   = (int*)alloc((size_t)2 * E * 4);
    int*   ebuf2   = (int*)alloc((size_t)2 * E * 4);
    (void)ws_size; (void)n_in; (void)out_size;

    const int GB64 = (N + 63) / 64;
    const int ECH = (2 * E + CHUNK - 1) / CHUNK;

    compute_M<<<(192 * 64 + 255) / 256, 256, 0, stream>>>(W3, Mt);
    prep_w<<<(2 * 64 * 128 + 255) / 256, 256, 0, stream>>>(W1_0, W1_1, W2_0, W2_1, W1t, W2t);

    // --- graph build ---
    hipMemsetAsync(bcnt, 0, (size_t)NBUCK * 4, stream);
    bcount<<<ECH, 256, 0, stream>>>(dst0, dst1, bcnt, N, E, NBUCK);
    bscan<<<1, 1024, 0, stream>>>(bcnt, bbase, bcursor, rowptr, NBUCK);
    bucket_scatter<<<ECH, 256, 0, stream>>>(src0, dst0, src1, dst1, bcursor, ebuf1, N, E, NBUCK);
    bucket_sort<<<NBUCK, 256, 0, stream>>>(ebuf1, bbase, ebuf2, rowptr, dinv, rsb, N2);

    // --- fused MLP (both branches), MFMA, no HBM intermediate ---
    mlp_mfma<<<2 * GB64, 256, 0, stream>>>(feat0, feat1, W1t, W2t,
                                           b1_0, b1_1, b2_0, b2_1, dinv, Hs, N, GB64);

    // --- polynomial propagation (bf16, node-sorted CSR) ---
    spmm_s<<<(N2 * 64 + 255) / 256, 256, 0, stream>>>(Hs, F1s, rowptr, ebuf2, dinv, N2);
    spmm_s<<<(N2 * 64 + 255) / 256, 256, 0, stream>>>(F1s, F2s, rowptr, ebuf2, dinv, N2);

    // --- final GEMM via MFMA, branch-folded ---
    gemmF_mfma<<<(N + 63) / 64, 256, 0, stream>>>(Hs, F1s, F2s, rsb, Mt, b3, out, N);
}